// Round 15
// baseline (555.891 us; speedup 1.0000x reference)
//
#include <hip/hip_runtime.h>
#include <math.h>

#define B_ 8
#define C_ 512
#define N_ 2048
#define M_ 2048
#define KSEL 614          /* int(2048*0.3) */
#define EPS_ 1e-5f
#define CS_ 8             /* c-chunks (C/64) for sq partials */
#define LDP 36            /* LDS row stride in ushorts: 72B=18 banks, period-16 -> 2-way max */

#define O_CORR 0
#define O_W    (B_*3*N_)          /* 49152 */
#define O_MSRC (O_W + B_*N_)      /* 65536 */
#define O_MTGT (O_MSRC + B_*N_)   /* 81920 */
#define O_ROT  (O_MTGT + B_*M_)   /* 98304 */
#define O_TR   (O_ROT + B_*9)     /* 98376 */

typedef short bf16x8 __attribute__((ext_vector_type(8)));
typedef float f32x4 __attribute__((ext_vector_type(4)));

__device__ inline unsigned short f2bf(float f){
  unsigned u = __float_as_uint(f);
  return (unsigned short)((u + 0x7FFFu + ((u >> 16) & 1u)) >> 16);
}
__device__ inline float bf2f(unsigned short h){
  return __uint_as_float(((unsigned)h) << 16);
}

__device__ inline double blk_sumd(double v, double* sh){
  int t = threadIdx.x;
  sh[t] = v; __syncthreads();
  for (int s = 128; s > 0; s >>= 1) { if (t < s) sh[t] += sh[t+s]; __syncthreads(); }
  double r = sh[0]; __syncthreads(); return r;
}

/* ---- combine sq partials -> xx/yy (y selects A/B side) ---- */
__global__ __launch_bounds__(256) void ksqcomb(const float* __restrict__ partA,
                                               const float* __restrict__ partB,
                                               float* __restrict__ xx,
                                               float* __restrict__ yy)
{
  int i = blockIdx.x*256 + threadIdx.x;
  const float* part = blockIdx.y ? partB : partA;
  float* out = blockIdx.y ? yy : xx;
  float s = 0.f;
  for (int cs = 0; cs < CS_; ++cs) s += part[(size_t)cs*B_*N_ + i];
  out[i] = s;
}

/* ---- split f32 [B][C][P] -> hi/lo bf16 [B][P][C] + fused sum-of-squares
        partials; z selects src_emb vs tgt_emb ---- */
__global__ __launch_bounds__(256) void ksplit(const float* __restrict__ XA,
                                              const float* __restrict__ XB,
                                              unsigned short* __restrict__ XhA,
                                              unsigned short* __restrict__ XlA,
                                              unsigned short* __restrict__ XhB,
                                              unsigned short* __restrict__ XlB,
                                              float* __restrict__ sqpartA,
                                              float* __restrict__ sqpartB)
{
  __shared__ float tile[64][65];  /* [p][c] */
  int p0 = blockIdx.x*64, c0 = blockIdx.y*64;
  int zb = blockIdx.z;
  int b = zb & (B_-1);
  int side = zb >> 3;
  const float* X = side ? XB : XA;
  unsigned short* Xh = side ? XhB : XhA;
  unsigned short* Xl = side ? XlB : XlA;
  float* sqpart = side ? sqpartB : sqpartA;
  int cs = blockIdx.y;
  int t = threadIdx.x;
  const float* base = X + ((size_t)b*C_ + c0)*N_ + p0;
  int px = (t & 15)*4, cy = t >> 4;
#pragma unroll
  for (int i = 0; i < 4; ++i) {
    int c = cy + i*16;
    float4 v = *(const float4*)(base + (size_t)c*N_ + px);
    tile[px+0][c] = v.x; tile[px+1][c] = v.y; tile[px+2][c] = v.z; tile[px+3][c] = v.w;
  }
  __syncthreads();
  int cx = (t & 15)*4, py = t >> 4;
  unsigned short* oh = Xh + ((size_t)b*N_ + p0)*C_ + c0;
  unsigned short* ol = Xl + ((size_t)b*N_ + p0)*C_ + c0;
#pragma unroll
  for (int i = 0; i < 4; ++i) {
    int p = py + i*16;
    float v0 = tile[p][cx], v1 = tile[p][cx+1], v2 = tile[p][cx+2], v3 = tile[p][cx+3];
    ushort4 h, l;
    h.x = f2bf(v0); l.x = f2bf(v0 - bf2f(h.x));
    h.y = f2bf(v1); l.y = f2bf(v1 - bf2f(h.y));
    h.z = f2bf(v2); l.z = f2bf(v2 - bf2f(h.z));
    h.w = f2bf(v3); l.w = f2bf(v3 - bf2f(h.w));
    *(ushort4*)(oh + (size_t)p*C_ + cx) = h;
    *(ushort4*)(ol + (size_t)p*C_ + cx) = l;
    float sqv = v0*v0 + v1*v1 + v2*v2 + v3*v3;
#pragma unroll
    for (int off = 1; off < 16; off <<= 1) sqv += __shfl_xor(sqv, off, 16);
    if ((t & 15) == 0) sqpart[((size_t)cs*B_ + b)*N_ + p0 + p] = sqv;
  }
}

/* ---- MFMA GEMM: E = exp(2*(Ah+Al)^T(Bh+Bl) - xx - yy), 3-term split-bf16.
        Named uint4 prefetch scalars. XCD-aware tile swizzle. LDS stride 36
        ushorts -> max 2-way bank aliasing (free). Epilogue fuses stat partials. */
__global__ __launch_bounds__(256, 1) void kgemm_mfma(
    const unsigned short* __restrict__ Ahg, const unsigned short* __restrict__ Alg,
    const unsigned short* __restrict__ Bhg, const unsigned short* __restrict__ Blg,
    const float* __restrict__ xx, const float* __restrict__ yy,
    float* __restrict__ E, float* __restrict__ rowps, float* __restrict__ rowpm,
    float* __restrict__ colps, int b_off)
{
  __shared__ unsigned short smem[4*128*LDP];   /* 36864 B */
  unsigned short* Ahs = smem;
  unsigned short* Als = smem + 128*LDP;
  unsigned short* Bhs = smem + 2*128*LDP;
  unsigned short* Bls = smem + 3*128*LDP;

  /* XCD swizzle (bijective permutation of the 16x16 tile grid) */
  int sflat = blockIdx.x + 16*blockIdx.y;     /* 0..255 */
  int xcd = sflat & 7, si = sflat >> 3;       /* si in 0..31 */
  int ka = xcd >> 1, kb = xcd & 1;
  int bn = ka*4 + (si & 3);
  int bm = kb*8 + (si >> 2);
  int bz = blockIdx.z;
  int b = b_off + bz;
  int t = threadIdx.x;
  size_t abase = ((size_t)b*N_ + (size_t)bn*128)*C_;
  size_t bbase = ((size_t)b*M_ + (size_t)bm*128)*C_;
  int g0 = t, g1 = t + 256;
  int r0 = g0 >> 2, c0g = (g0 & 3)*8;
  int r1 = g1 >> 2, c1g = (g1 & 3)*8;

  f32x4 acc[4][4];
#pragma unroll
  for (int i = 0; i < 4; ++i)
#pragma unroll
    for (int j = 0; j < 4; ++j) acc[i][j] = (f32x4){0.f, 0.f, 0.f, 0.f};

  uint4 p0, p1, p2, p3, p4, p5, p6, p7;   /* named scalars -> guaranteed VGPRs */
#define LOADS(K0) do { \
    p0 = *(const uint4*)(Ahg + abase + (size_t)r0*C_ + (K0) + c0g); \
    p1 = *(const uint4*)(Ahg + abase + (size_t)r1*C_ + (K0) + c1g); \
    p2 = *(const uint4*)(Alg + abase + (size_t)r0*C_ + (K0) + c0g); \
    p3 = *(const uint4*)(Alg + abase + (size_t)r1*C_ + (K0) + c1g); \
    p4 = *(const uint4*)(Bhg + bbase + (size_t)r0*C_ + (K0) + c0g); \
    p5 = *(const uint4*)(Bhg + bbase + (size_t)r1*C_ + (K0) + c1g); \
    p6 = *(const uint4*)(Blg + bbase + (size_t)r0*C_ + (K0) + c0g); \
    p7 = *(const uint4*)(Blg + bbase + (size_t)r1*C_ + (K0) + c1g); \
  } while (0)

  int lane = t & 63, w = t >> 6;
  int wr = (w >> 1)*64, wc = (w & 1)*64;
  int lrow = lane & 15, lgr = (lane >> 4)*8;

  LOADS(0);
  for (int ks = 0; ks < 16; ++ks) {
    __syncthreads();
    *(uint4*)&Ahs[r0*LDP + c0g] = p0;
    *(uint4*)&Ahs[r1*LDP + c1g] = p1;
    *(uint4*)&Als[r0*LDP + c0g] = p2;
    *(uint4*)&Als[r1*LDP + c1g] = p3;
    *(uint4*)&Bhs[r0*LDP + c0g] = p4;
    *(uint4*)&Bhs[r1*LDP + c1g] = p5;
    *(uint4*)&Bls[r0*LDP + c0g] = p6;
    *(uint4*)&Bls[r1*LDP + c1g] = p7;
    __syncthreads();
    if (ks < 15) { int k0n = (ks+1)*32; LOADS(k0n); }
    bf16x8 ah[4], al[4], bh[4], bl[4];
#pragma unroll
    for (int f = 0; f < 4; ++f) {
      int ra = (wr + f*16 + lrow)*LDP + lgr;
      int rb = (wc + f*16 + lrow)*LDP + lgr;
      ah[f] = *(const bf16x8*)&Ahs[ra];
      al[f] = *(const bf16x8*)&Als[ra];
      bh[f] = *(const bf16x8*)&Bhs[rb];
      bl[f] = *(const bf16x8*)&Bls[rb];
    }
#pragma unroll
    for (int fi = 0; fi < 4; ++fi)
#pragma unroll
      for (int fj = 0; fj < 4; ++fj) {
        acc[fi][fj] = __builtin_amdgcn_mfma_f32_16x16x32_bf16(ah[fi], bh[fj], acc[fi][fj], 0, 0, 0);
        acc[fi][fj] = __builtin_amdgcn_mfma_f32_16x16x32_bf16(ah[fi], bl[fj], acc[fi][fj], 0, 0, 0);
        acc[fi][fj] = __builtin_amdgcn_mfma_f32_16x16x32_bf16(al[fi], bh[fj], acc[fi][fj], 0, 0, 0);
      }
  }
#undef LOADS

  /* ---- two-pass epilogue (64x132 f32 LDS tile = 33792B <= 36864B) ---- */
  float* eps = (float*)smem;
  float* Eb = E + (size_t)bz*N_*M_;
  int lg = lane >> 4;                    /* 0..3 */
  int row0 = t >> 5;                     /* 0..7 */
  int c4 = (t & 31)*4;                   /* 0..124 */
  const float* yb = yy + b*M_ + bm*128;
  float4 vy = *(const float4*)(yb + c4);
  float ca0 = 0.f, ca1 = 0.f, ca2 = 0.f, ca3 = 0.f;   /* column partials */
#pragma unroll
  for (int pass = 0; pass < 2; ++pass) {
    __syncthreads();
    if ((w >> 1) == pass) {
#pragma unroll
      for (int fi = 0; fi < 4; ++fi) {
        int nl = lg*4 + fi*16;
#pragma unroll
        for (int fj = 0; fj < 4; ++fj) {
          int ml = wc + (lane & 15) + fj*16;
#pragma unroll
          for (int r = 0; r < 4; ++r)
            eps[(nl + r)*132 + ml] = acc[fi][fj][r];
        }
      }
    }
    __syncthreads();
#pragma unroll
    for (int it = 0; it < 8; ++it) {
      int row = it*8 + row0;
      int gn = bn*128 + pass*64 + row;
      float xv = xx[b*N_ + gn];
      float4 s = *(float4*)&eps[row*132 + c4];
      float4 o;
      o.x = expf(2.f*s.x - xv - vy.x);
      o.y = expf(2.f*s.y - xv - vy.y);
      o.z = expf(2.f*s.z - xv - vy.z);
      o.w = expf(2.f*s.w - xv - vy.w);
      *(float4*)(Eb + (size_t)gn*M_ + bm*128 + c4) = o;
      float rs = o.x + o.y + o.z + o.w;
      float rm2 = fmaxf(fmaxf(o.x, o.y), fmaxf(o.z, o.w));
      ca0 += o.x; ca1 += o.y; ca2 += o.z; ca3 += o.w;
#pragma unroll
      for (int off = 16; off > 0; off >>= 1) {
        rs += __shfl_xor(rs, off, 32);
        rm2 = fmaxf(rm2, __shfl_xor(rm2, off, 32));
      }
      if ((t & 31) == 0) {
        rowps[(size_t)bm*B_*N_ + (size_t)b*N_ + gn] = rs;
        rowpm[(size_t)bm*B_*N_ + (size_t)b*N_ + gn] = rm2;
      }
    }
  }
  __syncthreads();
  float* colsh = (float*)smem;           /* [8][128] */
  colsh[row0*128 + c4+0] = ca0;
  colsh[row0*128 + c4+1] = ca1;
  colsh[row0*128 + c4+2] = ca2;
  colsh[row0*128 + c4+3] = ca3;
  __syncthreads();
  if (t < 128) {
    float s = 0.f;
#pragma unroll
    for (int g = 0; g < 8; ++g) s += colsh[g*128 + t];
    colps[(size_t)bn*B_*M_ + (size_t)b*M_ + bm*128 + t] = s;
  }
}

/* ---- fused: y==0 -> rowZ/rowSmax from row partials; y==1 -> colZ0 ---- */
__global__ __launch_bounds__(256) void kstatcomb(
    const float* __restrict__ rowps, const float* __restrict__ rowpm,
    const float* __restrict__ colps,
    float* __restrict__ rowZf, float* __restrict__ rowSmax,
    float* __restrict__ colZ0f, int b_off)
{
  int i = blockIdx.x*256 + threadIdx.x;
  size_t gi = (size_t)b_off*N_ + i;
  if (blockIdx.y == 0) {
    double s = 0.0; float mx = 0.f;
#pragma unroll
    for (int k = 0; k < 16; ++k) {
      s += (double)rowps[(size_t)k*B_*N_ + gi];
      mx = fmaxf(mx, rowpm[(size_t)k*B_*N_ + gi]);
    }
    float zf = (float)s;
    rowZf[gi] = zf;
    rowSmax[gi] = mx * (1.f / zf);  /* same RN(1/zf) recomputed in kwcorr */
  } else {
    double s = 0.0;
#pragma unroll
    for (int k = 0; k < 16; ++k) s += (double)colps[(size_t)k*B_*M_ + gi];
    colZ0f[gi] = (float)s;
  }
}

/* ---- fused cross pass: one E read -> colSp (sum_n E/rowZ) AND rowSp
        (sum_m E/colZ0), f64 partials; reciprocals precomputed in LDS. ---- */
__global__ __launch_bounds__(256) void kcross(const float* __restrict__ E,
                                              const float* __restrict__ rowZf,
                                              const float* __restrict__ colZ0f,
                                              double* __restrict__ colSp,
                                              double* __restrict__ rowSp, int b_off)
{
  __shared__ float tile[64*129];   /* 33024 B */
  __shared__ double rzinv[64];
  __shared__ double czinv[128];
  __shared__ double shd[256];
  int rc = blockIdx.x, cc = blockIdx.y, bz = blockIdx.z;
  int b = b_off + bz;
  int r0 = rc*64, c0 = cc*128;
  int t = threadIdx.x;
  const float* Eb = E + (size_t)bz*N_*M_;
  {
    int rr = t >> 5, cq = (t & 31)*4;
#pragma unroll
    for (int it = 0; it < 8; ++it) {
      int row = it*8 + rr;
      float4 v = *(const float4*)(Eb + (size_t)(r0+row)*M_ + c0 + cq);
      tile[row*129 + cq+0] = v.x;
      tile[row*129 + cq+1] = v.y;
      tile[row*129 + cq+2] = v.z;
      tile[row*129 + cq+3] = v.w;
    }
  }
  if (t < 64) rzinv[t] = 1.0 / (double)rowZf[(size_t)b*N_ + r0 + t];
  if (t >= 128) czinv[t-128] = 1.0 / (double)colZ0f[(size_t)b*M_ + c0 + (t-128)];
  __syncthreads();
  {
    int j = t & 127, rg = t >> 7;
    double a = 0.0;
    for (int rr = rg*32; rr < rg*32 + 32; ++rr)
      a += (double)tile[rr*129 + j] * rzinv[rr];
    shd[rg*128 + j] = a;
  }
  __syncthreads();
  if (t < 128)
    colSp[(size_t)rc*B_*M_ + (size_t)b*M_ + c0 + t] = shd[t] + shd[128 + t];
  __syncthreads();
  {
    int r = t & 63, h = t >> 6;
    double a = 0.0;
    for (int j = h*32; j < h*32 + 32; ++j)
      a += (double)tile[r*129 + j] * czinv[j];
    shd[h*64 + r] = a;
  }
  __syncthreads();
  if (t < 64)
    rowSp[(size_t)cc*B_*N_ + (size_t)b*N_ + r0 + t] = shd[t] + shd[64+t] + shd[128+t] + shd[192+t];
}

/* ---- fused: y==0 -> col_sum (32 partials); y==1 -> row_sum (16 partials) ---- */
__global__ __launch_bounds__(256) void kcombab(const double* __restrict__ colSp,
                                               const double* __restrict__ rowSp,
                                               double* __restrict__ col_sum,
                                               double* __restrict__ row_sum, int b_off)
{
  int i = blockIdx.x*256 + threadIdx.x;
  if (blockIdx.y == 0) {
    size_t gi = (size_t)b_off*M_ + i;
    double s = 0.0;
    for (int k = 0; k < 32; ++k) s += colSp[(size_t)k*B_*M_ + gi];
    col_sum[gi] = s;
  } else {
    size_t gi = (size_t)b_off*N_ + i;
    double s = 0.0;
    for (int k = 0; k < 16; ++k) s += rowSp[(size_t)k*B_*N_ + gi];
    row_sum[gi] = s;
  }
}

/* ---- exact K-th smallest via rank count; z selects col/row side ---- */
__global__ __launch_bounds__(256) void kkth(const double* __restrict__ col_sum,
                                            const double* __restrict__ row_sum,
                                            double* __restrict__ kth_c,
                                            double* __restrict__ kth_r, int b_off)
{
  __shared__ double sv[2048];
  int b = b_off + blockIdx.y;
  const double* v = (blockIdx.z == 0 ? col_sum : row_sum) + b*2048;
  double* kth = (blockIdx.z == 0 ? kth_c : kth_r);
  int t = threadIdx.x;
  for (int i = t; i < 2048; i += 256) sv[i] = v[i];
  __syncthreads();
  int i = blockIdx.x*256 + t;
  double vi = sv[i];
  int lt = 0, le = 0;
  for (int j = 0; j < 2048; ++j) { double vj = sv[j]; lt += (vj < vi); le += (vj <= vi); }
  if (lt < KSEL && KSEL <= le) kth[b] = vi;
}

/* ---- masks; y selects col/row side ---- */
__global__ __launch_bounds__(256) void kmask(const double* __restrict__ col_sum,
                                             const double* __restrict__ row_sum,
                                             const double* __restrict__ kth_c,
                                             const double* __restrict__ kth_r,
                                             unsigned char* __restrict__ colmask,
                                             unsigned char* __restrict__ rowmask,
                                             float* __restrict__ out, int b_off)
{
  int side = blockIdx.y;
  const double* vals = side ? row_sum : col_sum;
  const double* kth = side ? kth_r : kth_c;
  unsigned char* m8 = side ? rowmask : colmask;
  float* mout = out + (side ? O_MSRC : O_MTGT);
  int i = blockIdx.x*256 + threadIdx.x;
  int b = b_off + i/2048, j = i & 2047;
  bool m = vals[b*2048 + j] < kth[b];
  m8[b*2048 + j] = m ? 1 : 0;
  mout[b*2048 + j] = m ? 1.f : 0.f;
}

/* ---- sparse renorm + vsi + src_corr: register-cached row (8 vals/thread),
        wave-shuffle reductions, reciprocal multiplies ---- */
__global__ __launch_bounds__(256) void kwcorr(
    const float* __restrict__ E, const float* __restrict__ rowZf,
    const float* __restrict__ rowSmax,
    const unsigned char* __restrict__ rowmask, const unsigned char* __restrict__ colmask,
    const float* __restrict__ tgt, float* __restrict__ vsi,
    float* __restrict__ corrf, float* __restrict__ corr_out, int b_off)
{
  __shared__ float shred[20];
  int r = blockIdx.x, t = threadIdx.x;
  int bz = r / N_, n = r % N_;
  int b = b_off + bz;
  const float* row = E + (size_t)bz*N_*M_ + (size_t)n*M_;
  float rinv = 1.f / rowZf[b*N_+n];       /* bit-identical to kstatcomb's rinv */
  int lane = t & 63, w = t >> 6;
  float rmax = rowSmax[b*N_+n];
  int rm = rowmask[b*N_+n];
  const unsigned char* cm = colmask + b*M_;
  float v[8];
  unsigned kp = 0;
  float s = 0.f;
#pragma unroll
  for (int il = 0; il < 8; ++il) {
    int m = t + il*256;
    float vv = row[m] * rinv;
    v[il] = vv;
    bool keep = rm || cm[m] || (vv >= rmax);
    kp |= (keep ? 1u : 0u) << il;
    if (keep) s += vv;
  }
#pragma unroll
  for (int off = 32; off; off >>= 1) s += __shfl_xor(s, off, 64);
  if (!lane) shred[w] = s;
  __syncthreads();
  s = shred[0] + shred[1] + shred[2] + shred[3];
  float d = (s < EPS_) ? EPS_ : s;
  float dinv = 1.f / d;
  const float* t0 = tgt + (size_t)b*3*M_;
  float vs = 0.f, a0 = 0.f, a1 = 0.f, a2 = 0.f;
#pragma unroll
  for (int il = 0; il < 8; ++il) {
    int m = t + il*256;
    float wv = (kp >> il & 1u) ? v[il]*dinv : 0.f;
    vs += wv;
    a0 += wv * t0[m];
    a1 += wv * t0[M_+m];
    a2 += wv * t0[2*M_+m];
  }
#pragma unroll
  for (int off = 32; off; off >>= 1) {
    vs += __shfl_xor(vs, off, 64);
    a0 += __shfl_xor(a0, off, 64);
    a1 += __shfl_xor(a1, off, 64);
    a2 += __shfl_xor(a2, off, 64);
  }
  if (!lane) {
    shred[4 + w] = vs; shred[8 + w] = a0; shred[12 + w] = a1; shred[16 + w] = a2;
  }
  __syncthreads();
  if (!t) {
    float vsT = shred[4]+shred[5]+shred[6]+shred[7];
    float a0T = shred[8]+shred[9]+shred[10]+shred[11];
    float a1T = shred[12]+shred[13]+shred[14]+shred[15];
    float a2T = shred[16]+shred[17]+shred[18]+shred[19];
    vsi[b*N_+n] = rm ? 0.f : vsT;
    size_t o = (size_t)b*3*N_ + n;
    corrf[o] = a0T; corrf[o+N_] = a1T; corrf[o+2*N_] = a2T;
    corr_out[o]      = a0T;
    corr_out[o+N_]   = a1T;
    corr_out[o+2*N_] = a2T;
  }
}

__global__ __launch_bounds__(256) void ksumvsi(const float* __restrict__ vsi,
                                               float* __restrict__ out)
{
  __shared__ double shd[256];
  int b = blockIdx.x;
  double s = 0.0;
  for (int n = threadIdx.x; n < N_; n += 256) s += (double)vsi[b*N_+n];
  s = blk_sumd(s, shd);
  if (!threadIdx.x) out[b] = (float)s;
}

__global__ __launch_bounds__(256) void kweights(const float* __restrict__ vsi,
                                                const float* __restrict__ sumvsi,
                                                float* __restrict__ srcw,
                                                float* __restrict__ wout)
{
  int i = blockIdx.x*256 + threadIdx.x;
  if (i >= B_*N_) return;
  int b = i / N_;
  float w = vsi[i] / sumvsi[b];
  srcw[i] = w;
  wout[i] = w;
}

__global__ __launch_bounds__(256) void kcov(const float* __restrict__ srcw,
                                            const float* __restrict__ src,
                                            const float* __restrict__ corrf,
                                            double* covd, double* cad, double* cbd)
{
  __shared__ double sh[256];
  int b = blockIdx.x, t = threadIdx.x;
  const float* w = srcw + b*N_;
  const float* a = src  + (size_t)b*3*N_;
  const float* bb = corrf + (size_t)b*3*N_;
  double sw = 0.0;
  for (int n = t; n < N_; n += 256) sw += (double)w[n];
  sw = blk_sumd(sw, sh);
  double inv = 1.0/(sw + 1e-5);
  double p0=0,p1=0,p2=0,p3=0,p4=0,p5=0;
  for (int n = t; n < N_; n += 256) {
    double wn = (double)w[n]*inv;
    p0 += (double)a[n]*wn;      p1 += (double)a[N_+n]*wn;   p2 += (double)a[2*N_+n]*wn;
    p3 += (double)bb[n]*wn;     p4 += (double)bb[N_+n]*wn;  p5 += (double)bb[2*N_+n]*wn;
  }
  double ca0 = blk_sumd(p0, sh), ca1 = blk_sumd(p1, sh), ca2 = blk_sumd(p2, sh);
  double cb0 = blk_sumd(p3, sh), cb1 = blk_sumd(p4, sh), cb2 = blk_sumd(p5, sh);
  double c[9] = {0,0,0,0,0,0,0,0,0};
  for (int n = t; n < N_; n += 256) {
    double wn = (double)w[n]*inv;
    double a0 = (double)a[n]-ca0, a1d = (double)a[N_+n]-ca1, a2d = (double)a[2*N_+n]-ca2;
    double b0 = ((double)bb[n]-cb0)*wn, b1 = ((double)bb[N_+n]-cb1)*wn, b2 = ((double)bb[2*N_+n]-cb2)*wn;
    c[0]+=a0*b0; c[1]+=a0*b1; c[2]+=a0*b2;
    c[3]+=a1d*b0; c[4]+=a1d*b1; c[5]+=a1d*b2;
    c[6]+=a2d*b0; c[7]+=a2d*b1; c[8]+=a2d*b2;
  }
  for (int k = 0; k < 9; ++k) {
    double rr = blk_sumd(c[k], sh);
    if (!t) covd[b*9+k] = rr;
  }
  if (!t) {
    cad[b*3+0]=ca0; cad[b*3+1]=ca1; cad[b*3+2]=ca2;
    cbd[b*3+0]=cb0; cbd[b*3+1]=cb1; cbd[b*3+2]=cb2;
  }
}

/* ---- 3x3 Kabsch via Jacobi eigendecomposition of H^T H (f64) ---- */
__global__ void ksvd(const double* __restrict__ covd, const double* __restrict__ cad,
                     const double* __restrict__ cbd, float* out)
{
  int b = threadIdx.x;
  if (b >= B_) return;
  double H[3][3];
  for (int i = 0; i < 3; ++i) for (int j = 0; j < 3; ++j) H[i][j] = covd[b*9+i*3+j];
  double A[3][3];
  for (int i = 0; i < 3; ++i)
    for (int j = 0; j < 3; ++j) {
      double s = 0.0;
      for (int l = 0; l < 3; ++l) s += H[l][i]*H[l][j];
      A[i][j] = s;
    }
  double V[3][3] = {{1,0,0},{0,1,0},{0,0,1}};
  const int PP[3] = {0,0,1}, QQ[3] = {1,2,2};
  for (int sweep = 0; sweep < 24; ++sweep) {
    double off = fabs(A[0][1])+fabs(A[0][2])+fabs(A[1][2]);
    if (off < 1e-28) break;
    for (int r = 0; r < 3; ++r) {
      int p = PP[r], q = QQ[r];
      double apq = A[p][q];
      if (fabs(apq) < 1e-300) continue;
      double th = (A[q][q]-A[p][p])/(2.0*apq);
      double tt = (th >= 0.0 ? 1.0 : -1.0)/(fabs(th)+sqrt(th*th+1.0));
      double cc = 1.0/sqrt(tt*tt+1.0), ss = tt*cc;
      for (int k = 0; k < 3; ++k) {
        double akp = A[k][p], akq = A[k][q];
        A[k][p] = cc*akp - ss*akq; A[k][q] = ss*akp + cc*akq;
      }
      for (int k = 0; k < 3; ++k) {
        double apk = A[p][k], aqk = A[q][k];
        A[p][k] = cc*apk - ss*aqk; A[q][k] = ss*apk + cc*aqk;
      }
      for (int k = 0; k < 3; ++k) {
        double vkp = V[k][p], vkq = V[k][q];
        V[k][p] = cc*vkp - ss*vkq; V[k][q] = ss*vkp + cc*vkq;
      }
    }
  }
  double lam[3] = {A[0][0], A[1][1], A[2][2]};
  int idx[3] = {0,1,2};
  for (int i = 0; i < 2; ++i)
    for (int j = i+1; j < 3; ++j)
      if (lam[idx[j]] > lam[idx[i]]) { int tmp = idx[i]; idx[i] = idx[j]; idx[j] = tmp; }
  double Vs[3][3], sig[3];
  for (int i = 0; i < 3; ++i) {
    for (int k = 0; k < 3; ++k) Vs[k][i] = V[k][idx[i]];
    double l = lam[idx[i]];
    sig[i] = sqrt(l > 0.0 ? l : 0.0);
  }
  double U[3][3];
  for (int i = 0; i < 3; ++i) {
    double inv = sig[i] > 1e-300 ? 1.0/sig[i] : 0.0;
    for (int k = 0; k < 3; ++k) {
      double u = H[k][0]*Vs[0][i] + H[k][1]*Vs[1][i] + H[k][2]*Vs[2][i];
      U[k][i] = u*inv;
    }
  }
  if (sig[2] <= 1e-9*sig[0]) {
    U[0][2] = U[1][0]*U[2][1] - U[2][0]*U[1][1];
    U[1][2] = U[2][0]*U[0][1] - U[0][0]*U[2][1];
    U[2][2] = U[0][0]*U[1][1] - U[1][0]*U[0][1];
  }
  double detH = H[0][0]*(H[1][1]*H[2][2]-H[1][2]*H[2][1])
              - H[0][1]*(H[1][0]*H[2][2]-H[1][2]*H[2][0])
              + H[0][2]*(H[1][0]*H[2][1]-H[1][1]*H[2][0]);
  double s3[3] = {1.0, 1.0, detH > 0.0 ? 1.0 : -1.0};
  double R[3][3];
  for (int d = 0; d < 3; ++d)
    for (int e = 0; e < 3; ++e) {
      double s = 0.0;
      for (int i = 0; i < 3; ++i) s += s3[i]*Vs[d][i]*U[e][i];
      R[d][e] = s;
    }
  double tr[3];
  for (int d = 0; d < 3; ++d)
    tr[d] = cbd[b*3+d] - (R[d][0]*cad[b*3+0] + R[d][1]*cad[b*3+1] + R[d][2]*cad[b*3+2]);
  for (int d = 0; d < 3; ++d)
    for (int e = 0; e < 3; ++e)
      out[O_ROT + b*9 + d*3 + e] = (float)R[d][e];
  for (int d = 0; d < 3; ++d)
    out[O_TR + b*3 + d] = (float)tr[d];
}

__global__ void kfail(float* out, float v) { out[0] = v; }

extern "C" void kernel_launch(void* const* d_in, const int* in_sizes, int n_in,
                              void* d_out, int out_size, void* d_ws, size_t ws_size,
                              hipStream_t stream) {
  float* out = (float*)d_out;
  (void)out_size;

  /* input-order auto-detect: dict (src,tgt,src_emb,tgt_emb) vs alphabetical */
  int i_tgt = 1, i_semb = 2;
  if (n_in == 4 && in_sizes[1] == B_*C_*N_) { i_semb = 1; i_tgt = 2; }
  const float* src  = (const float*)d_in[0];
  const float* tgt  = (const float*)d_in[i_tgt];
  const float* semb = (const float*)d_in[i_semb];
  const float* temb = (const float*)d_in[3];

  char* w = (char*)d_ws;
  auto alloc = [&](size_t bytes) { char* p = w; w += (bytes + 255)/256*256; return p; };
  float*  sqpartA = (float*)alloc((size_t)CS_*B_*N_*4);
  float*  sqpartB = (float*)alloc((size_t)CS_*B_*N_*4);
  float*  xx      = (float*)alloc((size_t)B_*N_*4);
  float*  yy      = (float*)alloc((size_t)B_*M_*4);
  float*  rowZf   = (float*)alloc((size_t)B_*N_*4);
  float*  rowSmax = (float*)alloc((size_t)B_*N_*4);
  float*  colZ0f  = (float*)alloc((size_t)B_*M_*4);
  float*  rowps   = (float*)alloc((size_t)16*B_*N_*4);   /* partial-major [bm][b][n] */
  float*  rowpm   = (float*)alloc((size_t)16*B_*N_*4);
  float*  colps   = (float*)alloc((size_t)16*B_*M_*4);   /* [bn][b][m] */
  double* colSp   = (double*)alloc((size_t)32*B_*M_*8);  /* [rc][b][m] */
  double* rowSp   = (double*)alloc((size_t)16*B_*N_*8);  /* [cc][b][n] */
  double* col_sum = (double*)alloc((size_t)B_*M_*8);
  double* row_sum = (double*)alloc((size_t)B_*N_*8);
  double* kth_c   = (double*)alloc((size_t)B_*8);
  double* kth_r   = (double*)alloc((size_t)B_*8);
  unsigned char* rowmask = (unsigned char*)alloc((size_t)B_*N_);
  unsigned char* colmask = (unsigned char*)alloc((size_t)B_*M_);
  float*  vsi     = (float*)alloc((size_t)B_*N_*4);
  float*  srcw    = (float*)alloc((size_t)B_*N_*4);
  float*  sumvsi  = (float*)alloc((size_t)B_*4);
  float*  corrf   = (float*)alloc((size_t)B_*3*N_*4);
  double* covd = (double*)alloc((size_t)B_*9*8);
  double* cad  = (double*)alloc((size_t)B_*3*8);
  double* cbd  = (double*)alloc((size_t)B_*3*8);
  /* split-bf16 operand arrays [B][pos][C] */
  unsigned short* Ahg = (unsigned short*)alloc((size_t)B_*N_*C_*2);
  unsigned short* Alg = (unsigned short*)alloc((size_t)B_*N_*C_*2);
  unsigned short* Bhg = (unsigned short*)alloc((size_t)B_*M_*C_*2);
  unsigned short* Blg = (unsigned short*)alloc((size_t)B_*M_*C_*2);

  size_t used = (size_t)(w - (char*)d_ws);
  size_t rem = ws_size > used ? ws_size - used : 0;
  size_t oneE = (size_t)N_*M_*sizeof(float);
  int bc = (int)(rem / oneE);
  if (bc < 1) { kfail<<<1, 1, 0, stream>>>(out, 32768.f); return; }
  if (bc > B_) bc = B_;
  float* E = (float*)w;

  /* split + transpose both embeddings (fused sum-of-squares partials) */
  ksplit<<<dim3(N_/64, C_/64, 2*B_), 256, 0, stream>>>(semb, temb, Ahg, Alg, Bhg, Blg,
                                                       sqpartA, sqpartB);
  ksqcomb<<<dim3((B_*N_)/256, 2), 256, 0, stream>>>(sqpartA, sqpartB, xx, yy);

  for (int b0 = 0; b0 < B_; b0 += bc) {
    int cur = (B_ - b0 < bc) ? (B_ - b0) : bc;
    kgemm_mfma<<<dim3(N_/128, M_/128, cur), 256, 0, stream>>>(Ahg, Alg, Bhg, Blg,
                                                              xx, yy, E, rowps, rowpm, colps, b0);
    kstatcomb<<<dim3(cur*N_/256, 2), 256, 0, stream>>>(rowps, rowpm, colps,
                                                       rowZf, rowSmax, colZ0f, b0);
    kcross   <<<dim3(N_/64, M_/128, cur), 256, 0, stream>>>(E, rowZf, colZ0f, colSp, rowSp, b0);
    kcombab  <<<dim3(cur*M_/256, 2), 256, 0, stream>>>(colSp, rowSp, col_sum, row_sum, b0);
    kkth     <<<dim3(8, cur, 2), 256, 0, stream>>>(col_sum, row_sum, kth_c, kth_r, b0);
    kmask    <<<dim3(cur*8, 2), 256, 0, stream>>>(col_sum, row_sum, kth_c, kth_r,
                                                  colmask, rowmask, out, b0);
    kwcorr   <<<cur*N_, 256, 0, stream>>>(E, rowZf, rowSmax, rowmask, colmask, tgt,
                                          vsi, corrf, out + O_CORR, b0);
  }

  ksumvsi <<<B_, 256, 0, stream>>>(vsi, sumvsi);
  kweights<<<(B_*N_+255)/256, 256, 0, stream>>>(vsi, sumvsi, srcw, out + O_W);
  kcov    <<<B_, 256, 0, stream>>>(srcw, src, corrf, covd, cad, cbd);
  ksvd    <<<1, 64, 0, stream>>>(covd, cad, cbd, out);
}

// Round 16
// 309.962 us; speedup vs baseline: 1.7934x; 1.7934x over previous
//
#include <hip/hip_runtime.h>
#include <math.h>

#define B_ 8
#define C_ 512
#define N_ 2048
#define M_ 2048
#define KSEL 614          /* int(2048*0.3) */
#define EPS_ 1e-5f
#define CS_ 8             /* c-chunks (C/64) for sq partials */

#define O_CORR 0
#define O_W    (B_*3*N_)          /* 49152 */
#define O_MSRC (O_W + B_*N_)      /* 65536 */
#define O_MTGT (O_MSRC + B_*N_)   /* 81920 */
#define O_ROT  (O_MTGT + B_*M_)   /* 98304 */
#define O_TR   (O_ROT + B_*9)     /* 98376 */

typedef short bf16x8 __attribute__((ext_vector_type(8)));
typedef float f32x4 __attribute__((ext_vector_type(4)));

__device__ inline unsigned short f2bf(float f){
  unsigned u = __float_as_uint(f);
  return (unsigned short)((u + 0x7FFFu + ((u >> 16) & 1u)) >> 16);
}
__device__ inline float bf2f(unsigned short h){
  return __uint_as_float(((unsigned)h) << 16);
}

__device__ inline double blk_sumd(double v, double* sh){
  int t = threadIdx.x;
  sh[t] = v; __syncthreads();
  for (int s = 128; s > 0; s >>= 1) { if (t < s) sh[t] += sh[t+s]; __syncthreads(); }
  double r = sh[0]; __syncthreads(); return r;
}

/* ---- combine sq partials -> xx/yy (y selects A/B side) ---- */
__global__ __launch_bounds__(256) void ksqcomb(const float* __restrict__ partA,
                                               const float* __restrict__ partB,
                                               float* __restrict__ xx,
                                               float* __restrict__ yy)
{
  int i = blockIdx.x*256 + threadIdx.x;
  const float* part = blockIdx.y ? partB : partA;
  float* out = blockIdx.y ? yy : xx;
  float s = 0.f;
  for (int cs = 0; cs < CS_; ++cs) s += part[(size_t)cs*B_*N_ + i];
  out[i] = s;
}

/* ---- split f32 [B][C][P] -> hi/lo bf16 [B][P][C] + fused sum-of-squares
        partials; z selects src_emb vs tgt_emb ---- */
__global__ __launch_bounds__(256) void ksplit(const float* __restrict__ XA,
                                              const float* __restrict__ XB,
                                              unsigned short* __restrict__ XhA,
                                              unsigned short* __restrict__ XlA,
                                              unsigned short* __restrict__ XhB,
                                              unsigned short* __restrict__ XlB,
                                              float* __restrict__ sqpartA,
                                              float* __restrict__ sqpartB)
{
  __shared__ float tile[64][65];  /* [p][c] */
  int p0 = blockIdx.x*64, c0 = blockIdx.y*64;
  int zb = blockIdx.z;
  int b = zb & (B_-1);
  int side = zb >> 3;
  const float* X = side ? XB : XA;
  unsigned short* Xh = side ? XhB : XhA;
  unsigned short* Xl = side ? XlB : XlA;
  float* sqpart = side ? sqpartB : sqpartA;
  int cs = blockIdx.y;
  int t = threadIdx.x;
  const float* base = X + ((size_t)b*C_ + c0)*N_ + p0;
  int px = (t & 15)*4, cy = t >> 4;
#pragma unroll
  for (int i = 0; i < 4; ++i) {
    int c = cy + i*16;
    float4 v = *(const float4*)(base + (size_t)c*N_ + px);
    tile[px+0][c] = v.x; tile[px+1][c] = v.y; tile[px+2][c] = v.z; tile[px+3][c] = v.w;
  }
  __syncthreads();
  int cx = (t & 15)*4, py = t >> 4;
  unsigned short* oh = Xh + ((size_t)b*N_ + p0)*C_ + c0;
  unsigned short* ol = Xl + ((size_t)b*N_ + p0)*C_ + c0;
#pragma unroll
  for (int i = 0; i < 4; ++i) {
    int p = py + i*16;
    float v0 = tile[p][cx], v1 = tile[p][cx+1], v2 = tile[p][cx+2], v3 = tile[p][cx+3];
    ushort4 h, l;
    h.x = f2bf(v0); l.x = f2bf(v0 - bf2f(h.x));
    h.y = f2bf(v1); l.y = f2bf(v1 - bf2f(h.y));
    h.z = f2bf(v2); l.z = f2bf(v2 - bf2f(h.z));
    h.w = f2bf(v3); l.w = f2bf(v3 - bf2f(h.w));
    *(ushort4*)(oh + (size_t)p*C_ + cx) = h;
    *(ushort4*)(ol + (size_t)p*C_ + cx) = l;
    float sqv = v0*v0 + v1*v1 + v2*v2 + v3*v3;
#pragma unroll
    for (int off = 1; off < 16; off <<= 1) sqv += __shfl_xor(sqv, off, 16);
    if ((t & 15) == 0) sqpart[((size_t)cs*B_ + b)*N_ + p0 + p] = sqv;
  }
}

/* ---- MFMA GEMM: E = exp(2*(Ah+Al)^T(Bh+Bl) - xx - yy), 3-term split-bf16.
        m97 structure: global_load_lds width-16 into linear [128][32] ushort
        tiles (64B rows: 16B-aligned, uniform 8 lanes/bank-quad -> conflict-free),
        double-buffered, one barrier per K-step (barrier drains vmcnt).
        XCD-aware tile swizzle. Epilogue fuses row/col stat partials. ---- */
__global__ __launch_bounds__(256, 1) void kgemm_mfma(
    const unsigned short* __restrict__ Ahg, const unsigned short* __restrict__ Alg,
    const unsigned short* __restrict__ Bhg, const unsigned short* __restrict__ Blg,
    const float* __restrict__ xx, const float* __restrict__ yy,
    float* __restrict__ E, float* __restrict__ rowps, float* __restrict__ rowpm,
    float* __restrict__ colps, int b_off)
{
  __shared__ unsigned short smem[2*4*128*32];   /* 65536 B: 2 bufs x 4 ops x 8KB */

  /* XCD swizzle (bijective permutation of the 16x16 tile grid) */
  int sflat = blockIdx.x + 16*blockIdx.y;     /* 0..255 */
  int xcd = sflat & 7, si = sflat >> 3;       /* si in 0..31 */
  int ka = xcd >> 1, kb = xcd & 1;
  int bn = ka*4 + (si & 3);
  int bm = kb*8 + (si >> 2);
  int bz = blockIdx.z;
  int b = b_off + bz;
  int t = threadIdx.x;
  int lane = t & 63, w = t >> 6;
  int wr = (w >> 1)*64, wc = (w & 1)*64;
  int lrow = lane & 15, lgr = (lane >> 4)*8;
  size_t abase = ((size_t)b*N_ + (size_t)bn*128)*C_;
  size_t bbase = ((size_t)b*M_ + (size_t)bm*128)*C_;
  int lr4 = lane >> 2;          /* 0..15: row within 16-row chunk */
  int lc4 = (lane & 3)*8;       /* ushort col offset: 0,8,16,24 */

  f32x4 acc[4][4];
#pragma unroll
  for (int i = 0; i < 4; ++i)
#pragma unroll
    for (int j = 0; j < 4; ++j) acc[i][j] = (f32x4){0.f, 0.f, 0.f, 0.f};

  /* issue async global->LDS for one K-slice into buffer bufk.
     Each wave covers 2 chunks x 16 rows x 64B per operand. LDS dest is
     wave-uniform base; HW scatters lane l at base + l*16B. */
#define ISSUE(bufk, K0) do { \
    unsigned short* bb0 = smem + (bufk)*16384; \
    _Pragma("unroll") \
    for (int q = 0; q < 2; ++q) { \
      int rblk = w*2 + q; \
      size_t roff = (size_t)(rblk*16 + lr4)*C_ + (K0) + lc4; \
      unsigned short* ldsb = bb0 + rblk*512; \
      __builtin_amdgcn_global_load_lds((const void*)(Ahg + abase + roff), (void*)(ldsb),         16, 0, 0); \
      __builtin_amdgcn_global_load_lds((const void*)(Alg + abase + roff), (void*)(ldsb + 4096),  16, 0, 0); \
      __builtin_amdgcn_global_load_lds((const void*)(Bhg + bbase + roff), (void*)(ldsb + 8192),  16, 0, 0); \
      __builtin_amdgcn_global_load_lds((const void*)(Blg + bbase + roff), (void*)(ldsb + 12288), 16, 0, 0); \
    } \
  } while (0)

  ISSUE(0, 0);
  int cur = 0;
  for (int ks = 0; ks < 16; ++ks) {
    __syncthreads();                  /* drains this wave's gload vmcnt + syncs */
    if (ks < 15) { int k0n = (ks+1)*32; ISSUE(cur^1, k0n); }
    unsigned short* bb = smem + cur*16384;
    unsigned short* Ahs = bb;
    unsigned short* Als = bb + 4096;
    unsigned short* Bhs = bb + 8192;
    unsigned short* Bls = bb + 12288;
    bf16x8 ah[4], al[4], bh[4], bl[4];
#pragma unroll
    for (int f = 0; f < 4; ++f) {
      int ra = (wr + f*16 + lrow)*32 + lgr;
      int rb = (wc + f*16 + lrow)*32 + lgr;
      ah[f] = *(const bf16x8*)&Ahs[ra];
      al[f] = *(const bf16x8*)&Als[ra];
      bh[f] = *(const bf16x8*)&Bhs[rb];
      bl[f] = *(const bf16x8*)&Bls[rb];
    }
#pragma unroll
    for (int fi = 0; fi < 4; ++fi)
#pragma unroll
      for (int fj = 0; fj < 4; ++fj) {
        acc[fi][fj] = __builtin_amdgcn_mfma_f32_16x16x32_bf16(ah[fi], bh[fj], acc[fi][fj], 0, 0, 0);
        acc[fi][fj] = __builtin_amdgcn_mfma_f32_16x16x32_bf16(ah[fi], bl[fj], acc[fi][fj], 0, 0, 0);
        acc[fi][fj] = __builtin_amdgcn_mfma_f32_16x16x32_bf16(al[fi], bh[fj], acc[fi][fj], 0, 0, 0);
      }
    cur ^= 1;
  }
#undef ISSUE

  /* ---- two-pass epilogue (64x132 f32 LDS tile = 33792B <= 65536B) ---- */
  float* eps = (float*)smem;
  float* Eb = E + (size_t)bz*N_*M_;
  int lg = lane >> 4;                    /* 0..3 */
  int row0 = t >> 5;                     /* 0..7 */
  int c4 = (t & 31)*4;                   /* 0..124 */
  const float* yb = yy + b*M_ + bm*128;
  float4 vy = *(const float4*)(yb + c4);
  float ca0 = 0.f, ca1 = 0.f, ca2 = 0.f, ca3 = 0.f;   /* column partials */
#pragma unroll
  for (int pass = 0; pass < 2; ++pass) {
    __syncthreads();
    if ((w >> 1) == pass) {
#pragma unroll
      for (int fi = 0; fi < 4; ++fi) {
        int nl = lg*4 + fi*16;
#pragma unroll
        for (int fj = 0; fj < 4; ++fj) {
          int ml = wc + (lane & 15) + fj*16;
#pragma unroll
          for (int r = 0; r < 4; ++r)
            eps[(nl + r)*132 + ml] = acc[fi][fj][r];
        }
      }
    }
    __syncthreads();
#pragma unroll
    for (int it = 0; it < 8; ++it) {
      int row = it*8 + row0;
      int gn = bn*128 + pass*64 + row;
      float xv = xx[b*N_ + gn];
      float4 s = *(float4*)&eps[row*132 + c4];
      float4 o;
      o.x = expf(2.f*s.x - xv - vy.x);
      o.y = expf(2.f*s.y - xv - vy.y);
      o.z = expf(2.f*s.z - xv - vy.z);
      o.w = expf(2.f*s.w - xv - vy.w);
      *(float4*)(Eb + (size_t)gn*M_ + bm*128 + c4) = o;
      float rs = o.x + o.y + o.z + o.w;
      float rm2 = fmaxf(fmaxf(o.x, o.y), fmaxf(o.z, o.w));
      ca0 += o.x; ca1 += o.y; ca2 += o.z; ca3 += o.w;
#pragma unroll
      for (int off = 16; off > 0; off >>= 1) {
        rs += __shfl_xor(rs, off, 32);
        rm2 = fmaxf(rm2, __shfl_xor(rm2, off, 32));
      }
      if ((t & 31) == 0) {
        rowps[(size_t)bm*B_*N_ + (size_t)b*N_ + gn] = rs;
        rowpm[(size_t)bm*B_*N_ + (size_t)b*N_ + gn] = rm2;
      }
    }
  }
  __syncthreads();
  float* colsh = (float*)smem;           /* [8][128] */
  colsh[row0*128 + c4+0] = ca0;
  colsh[row0*128 + c4+1] = ca1;
  colsh[row0*128 + c4+2] = ca2;
  colsh[row0*128 + c4+3] = ca3;
  __syncthreads();
  if (t < 128) {
    float s = 0.f;
#pragma unroll
    for (int g = 0; g < 8; ++g) s += colsh[g*128 + t];
    colps[(size_t)bn*B_*M_ + (size_t)b*M_ + bm*128 + t] = s;
  }
}

/* ---- fused: y==0 -> rowZ/rowSmax from row partials; y==1 -> colZ0 ---- */
__global__ __launch_bounds__(256) void kstatcomb(
    const float* __restrict__ rowps, const float* __restrict__ rowpm,
    const float* __restrict__ colps,
    float* __restrict__ rowZf, float* __restrict__ rowSmax,
    float* __restrict__ colZ0f, int b_off)
{
  int i = blockIdx.x*256 + threadIdx.x;
  size_t gi = (size_t)b_off*N_ + i;
  if (blockIdx.y == 0) {
    double s = 0.0; float mx = 0.f;
#pragma unroll
    for (int k = 0; k < 16; ++k) {
      s += (double)rowps[(size_t)k*B_*N_ + gi];
      mx = fmaxf(mx, rowpm[(size_t)k*B_*N_ + gi]);
    }
    float zf = (float)s;
    rowZf[gi] = zf;
    rowSmax[gi] = mx * (1.f / zf);  /* same RN(1/zf) recomputed in kwcorr */
  } else {
    double s = 0.0;
#pragma unroll
    for (int k = 0; k < 16; ++k) s += (double)colps[(size_t)k*B_*M_ + gi];
    colZ0f[gi] = (float)s;
  }
}

/* ---- fused cross pass: one E read -> colSp (sum_n E/rowZ) AND rowSp
        (sum_m E/colZ0), f64 partials; reciprocals precomputed in LDS. ---- */
__global__ __launch_bounds__(256) void kcross(const float* __restrict__ E,
                                              const float* __restrict__ rowZf,
                                              const float* __restrict__ colZ0f,
                                              double* __restrict__ colSp,
                                              double* __restrict__ rowSp, int b_off)
{
  __shared__ float tile[64*129];   /* 33024 B */
  __shared__ double rzinv[64];
  __shared__ double czinv[128];
  __shared__ double shd[256];
  int rc = blockIdx.x, cc = blockIdx.y, bz = blockIdx.z;
  int b = b_off + bz;
  int r0 = rc*64, c0 = cc*128;
  int t = threadIdx.x;
  const float* Eb = E + (size_t)bz*N_*M_;
  {
    int rr = t >> 5, cq = (t & 31)*4;
#pragma unroll
    for (int it = 0; it < 8; ++it) {
      int row = it*8 + rr;
      float4 v = *(const float4*)(Eb + (size_t)(r0+row)*M_ + c0 + cq);
      tile[row*129 + cq+0] = v.x;
      tile[row*129 + cq+1] = v.y;
      tile[row*129 + cq+2] = v.z;
      tile[row*129 + cq+3] = v.w;
    }
  }
  if (t < 64) rzinv[t] = 1.0 / (double)rowZf[(size_t)b*N_ + r0 + t];
  if (t >= 128) czinv[t-128] = 1.0 / (double)colZ0f[(size_t)b*M_ + c0 + (t-128)];
  __syncthreads();
  {
    int j = t & 127, rg = t >> 7;
    double a = 0.0;
    for (int rr = rg*32; rr < rg*32 + 32; ++rr)
      a += (double)tile[rr*129 + j] * rzinv[rr];
    shd[rg*128 + j] = a;
  }
  __syncthreads();
  if (t < 128)
    colSp[(size_t)rc*B_*M_ + (size_t)b*M_ + c0 + t] = shd[t] + shd[128 + t];
  __syncthreads();
  {
    int r = t & 63, h = t >> 6;
    double a = 0.0;
    for (int j = h*32; j < h*32 + 32; ++j)
      a += (double)tile[r*129 + j] * czinv[j];
    shd[h*64 + r] = a;
  }
  __syncthreads();
  if (t < 64)
    rowSp[(size_t)cc*B_*N_ + (size_t)b*N_ + r0 + t] = shd[t] + shd[64+t] + shd[128+t] + shd[192+t];
}

/* ---- fused: y==0 -> col_sum (32 partials); y==1 -> row_sum (16 partials) ---- */
__global__ __launch_bounds__(256) void kcombab(const double* __restrict__ colSp,
                                               const double* __restrict__ rowSp,
                                               double* __restrict__ col_sum,
                                               double* __restrict__ row_sum, int b_off)
{
  int i = blockIdx.x*256 + threadIdx.x;
  if (blockIdx.y == 0) {
    size_t gi = (size_t)b_off*M_ + i;
    double s = 0.0;
    for (int k = 0; k < 32; ++k) s += colSp[(size_t)k*B_*M_ + gi];
    col_sum[gi] = s;
  } else {
    size_t gi = (size_t)b_off*N_ + i;
    double s = 0.0;
    for (int k = 0; k < 16; ++k) s += rowSp[(size_t)k*B_*N_ + gi];
    row_sum[gi] = s;
  }
}

/* ---- exact K-th smallest via rank count; z selects col/row side ---- */
__global__ __launch_bounds__(256) void kkth(const double* __restrict__ col_sum,
                                            const double* __restrict__ row_sum,
                                            double* __restrict__ kth_c,
                                            double* __restrict__ kth_r, int b_off)
{
  __shared__ double sv[2048];
  int b = b_off + blockIdx.y;
  const double* v = (blockIdx.z == 0 ? col_sum : row_sum) + b*2048;
  double* kth = (blockIdx.z == 0 ? kth_c : kth_r);
  int t = threadIdx.x;
  for (int i = t; i < 2048; i += 256) sv[i] = v[i];
  __syncthreads();
  int i = blockIdx.x*256 + t;
  double vi = sv[i];
  int lt = 0, le = 0;
  for (int j = 0; j < 2048; ++j) { double vj = sv[j]; lt += (vj < vi); le += (vj <= vi); }
  if (lt < KSEL && KSEL <= le) kth[b] = vi;
}

/* ---- masks; y selects col/row side ---- */
__global__ __launch_bounds__(256) void kmask(const double* __restrict__ col_sum,
                                             const double* __restrict__ row_sum,
                                             const double* __restrict__ kth_c,
                                             const double* __restrict__ kth_r,
                                             unsigned char* __restrict__ colmask,
                                             unsigned char* __restrict__ rowmask,
                                             float* __restrict__ out, int b_off)
{
  int side = blockIdx.y;
  const double* vals = side ? row_sum : col_sum;
  const double* kth = side ? kth_r : kth_c;
  unsigned char* m8 = side ? rowmask : colmask;
  float* mout = out + (side ? O_MSRC : O_MTGT);
  int i = blockIdx.x*256 + threadIdx.x;
  int b = b_off + i/2048, j = i & 2047;
  bool m = vals[b*2048 + j] < kth[b];
  m8[b*2048 + j] = m ? 1 : 0;
  mout[b*2048 + j] = m ? 1.f : 0.f;
}

/* ---- sparse renorm + vsi + src_corr: register-cached row (8 vals/thread),
        wave-shuffle reductions, reciprocal multiplies ---- */
__global__ __launch_bounds__(256) void kwcorr(
    const float* __restrict__ E, const float* __restrict__ rowZf,
    const float* __restrict__ rowSmax,
    const unsigned char* __restrict__ rowmask, const unsigned char* __restrict__ colmask,
    const float* __restrict__ tgt, float* __restrict__ vsi,
    float* __restrict__ corrf, float* __restrict__ corr_out, int b_off)
{
  __shared__ float shred[20];
  int r = blockIdx.x, t = threadIdx.x;
  int bz = r / N_, n = r % N_;
  int b = b_off + bz;
  const float* row = E + (size_t)bz*N_*M_ + (size_t)n*M_;
  float rinv = 1.f / rowZf[b*N_+n];       /* bit-identical to kstatcomb's rinv */
  int lane = t & 63, w = t >> 6;
  float rmax = rowSmax[b*N_+n];
  int rm = rowmask[b*N_+n];
  const unsigned char* cm = colmask + b*M_;
  float v[8];
  unsigned kp = 0;
  float s = 0.f;
#pragma unroll
  for (int il = 0; il < 8; ++il) {
    int m = t + il*256;
    float vv = row[m] * rinv;
    v[il] = vv;
    bool keep = rm || cm[m] || (vv >= rmax);
    kp |= (keep ? 1u : 0u) << il;
    if (keep) s += vv;
  }
#pragma unroll
  for (int off = 32; off; off >>= 1) s += __shfl_xor(s, off, 64);
  if (!lane) shred[w] = s;
  __syncthreads();
  s = shred[0] + shred[1] + shred[2] + shred[3];
  float d = (s < EPS_) ? EPS_ : s;
  float dinv = 1.f / d;
  const float* t0 = tgt + (size_t)b*3*M_;
  float vs = 0.f, a0 = 0.f, a1 = 0.f, a2 = 0.f;
#pragma unroll
  for (int il = 0; il < 8; ++il) {
    int m = t + il*256;
    float wv = (kp >> il & 1u) ? v[il]*dinv : 0.f;
    vs += wv;
    a0 += wv * t0[m];
    a1 += wv * t0[M_+m];
    a2 += wv * t0[2*M_+m];
  }
#pragma unroll
  for (int off = 32; off; off >>= 1) {
    vs += __shfl_xor(vs, off, 64);
    a0 += __shfl_xor(a0, off, 64);
    a1 += __shfl_xor(a1, off, 64);
    a2 += __shfl_xor(a2, off, 64);
  }
  if (!lane) {
    shred[4 + w] = vs; shred[8 + w] = a0; shred[12 + w] = a1; shred[16 + w] = a2;
  }
  __syncthreads();
  if (!t) {
    float vsT = shred[4]+shred[5]+shred[6]+shred[7];
    float a0T = shred[8]+shred[9]+shred[10]+shred[11];
    float a1T = shred[12]+shred[13]+shred[14]+shred[15];
    float a2T = shred[16]+shred[17]+shred[18]+shred[19];
    vsi[b*N_+n] = rm ? 0.f : vsT;
    size_t o = (size_t)b*3*N_ + n;
    corrf[o] = a0T; corrf[o+N_] = a1T; corrf[o+2*N_] = a2T;
    corr_out[o]      = a0T;
    corr_out[o+N_]   = a1T;
    corr_out[o+2*N_] = a2T;
  }
}

__global__ __launch_bounds__(256) void ksumvsi(const float* __restrict__ vsi,
                                               float* __restrict__ out)
{
  __shared__ double shd[256];
  int b = blockIdx.x;
  double s = 0.0;
  for (int n = threadIdx.x; n < N_; n += 256) s += (double)vsi[b*N_+n];
  s = blk_sumd(s, shd);
  if (!threadIdx.x) out[b] = (float)s;
}

__global__ __launch_bounds__(256) void kweights(const float* __restrict__ vsi,
                                                const float* __restrict__ sumvsi,
                                                float* __restrict__ srcw,
                                                float* __restrict__ wout)
{
  int i = blockIdx.x*256 + threadIdx.x;
  if (i >= B_*N_) return;
  int b = i / N_;
  float w = vsi[i] / sumvsi[b];
  srcw[i] = w;
  wout[i] = w;
}

__global__ __launch_bounds__(256) void kcov(const float* __restrict__ srcw,
                                            const float* __restrict__ src,
                                            const float* __restrict__ corrf,
                                            double* covd, double* cad, double* cbd)
{
  __shared__ double sh[256];
  int b = blockIdx.x, t = threadIdx.x;
  const float* w = srcw + b*N_;
  const float* a = src  + (size_t)b*3*N_;
  const float* bb = corrf + (size_t)b*3*N_;
  double sw = 0.0;
  for (int n = t; n < N_; n += 256) sw += (double)w[n];
  sw = blk_sumd(sw, sh);
  double inv = 1.0/(sw + 1e-5);
  double p0=0,p1=0,p2=0,p3=0,p4=0,p5=0;
  for (int n = t; n < N_; n += 256) {
    double wn = (double)w[n]*inv;
    p0 += (double)a[n]*wn;      p1 += (double)a[N_+n]*wn;   p2 += (double)a[2*N_+n]*wn;
    p3 += (double)bb[n]*wn;     p4 += (double)bb[N_+n]*wn;  p5 += (double)bb[2*N_+n]*wn;
  }
  double ca0 = blk_sumd(p0, sh), ca1 = blk_sumd(p1, sh), ca2 = blk_sumd(p2, sh);
  double cb0 = blk_sumd(p3, sh), cb1 = blk_sumd(p4, sh), cb2 = blk_sumd(p5, sh);
  double c[9] = {0,0,0,0,0,0,0,0,0};
  for (int n = t; n < N_; n += 256) {
    double wn = (double)w[n]*inv;
    double a0 = (double)a[n]-ca0, a1d = (double)a[N_+n]-ca1, a2d = (double)a[2*N_+n]-ca2;
    double b0 = ((double)bb[n]-cb0)*wn, b1 = ((double)bb[N_+n]-cb1)*wn, b2 = ((double)bb[2*N_+n]-cb2)*wn;
    c[0]+=a0*b0; c[1]+=a0*b1; c[2]+=a0*b2;
    c[3]+=a1d*b0; c[4]+=a1d*b1; c[5]+=a1d*b2;
    c[6]+=a2d*b0; c[7]+=a2d*b1; c[8]+=a2d*b2;
  }
  for (int k = 0; k < 9; ++k) {
    double rr = blk_sumd(c[k], sh);
    if (!t) covd[b*9+k] = rr;
  }
  if (!t) {
    cad[b*3+0]=ca0; cad[b*3+1]=ca1; cad[b*3+2]=ca2;
    cbd[b*3+0]=cb0; cbd[b*3+1]=cb1; cbd[b*3+2]=cb2;
  }
}

/* ---- 3x3 Kabsch via Jacobi eigendecomposition of H^T H (f64) ---- */
__global__ void ksvd(const double* __restrict__ covd, const double* __restrict__ cad,
                     const double* __restrict__ cbd, float* out)
{
  int b = threadIdx.x;
  if (b >= B_) return;
  double H[3][3];
  for (int i = 0; i < 3; ++i) for (int j = 0; j < 3; ++j) H[i][j] = covd[b*9+i*3+j];
  double A[3][3];
  for (int i = 0; i < 3; ++i)
    for (int j = 0; j < 3; ++j) {
      double s = 0.0;
      for (int l = 0; l < 3; ++l) s += H[l][i]*H[l][j];
      A[i][j] = s;
    }
  double V[3][3] = {{1,0,0},{0,1,0},{0,0,1}};
  const int PP[3] = {0,0,1}, QQ[3] = {1,2,2};
  for (int sweep = 0; sweep < 24; ++sweep) {
    double off = fabs(A[0][1])+fabs(A[0][2])+fabs(A[1][2]);
    if (off < 1e-28) break;
    for (int r = 0; r < 3; ++r) {
      int p = PP[r], q = QQ[r];
      double apq = A[p][q];
      if (fabs(apq) < 1e-300) continue;
      double th = (A[q][q]-A[p][p])/(2.0*apq);
      double tt = (th >= 0.0 ? 1.0 : -1.0)/(fabs(th)+sqrt(th*th+1.0));
      double cc = 1.0/sqrt(tt*tt+1.0), ss = tt*cc;
      for (int k = 0; k < 3; ++k) {
        double akp = A[k][p], akq = A[k][q];
        A[k][p] = cc*akp - ss*akq; A[k][q] = ss*akp + cc*akq;
      }
      for (int k = 0; k < 3; ++k) {
        double apk = A[p][k], aqk = A[q][k];
        A[p][k] = cc*apk - ss*aqk; A[q][k] = ss*apk + cc*aqk;
      }
      for (int k = 0; k < 3; ++k) {
        double vkp = V[k][p], vkq = V[k][q];
        V[k][p] = cc*vkp - ss*vkq; V[k][q] = ss*vkp + cc*vkq;
      }
    }
  }
  double lam[3] = {A[0][0], A[1][1], A[2][2]};
  int idx[3] = {0,1,2};
  for (int i = 0; i < 2; ++i)
    for (int j = i+1; j < 3; ++j)
      if (lam[idx[j]] > lam[idx[i]]) { int tmp = idx[i]; idx[i] = idx[j]; idx[j] = tmp; }
  double Vs[3][3], sig[3];
  for (int i = 0; i < 3; ++i) {
    for (int k = 0; k < 3; ++k) Vs[k][i] = V[k][idx[i]];
    double l = lam[idx[i]];
    sig[i] = sqrt(l > 0.0 ? l : 0.0);
  }
  double U[3][3];
  for (int i = 0; i < 3; ++i) {
    double inv = sig[i] > 1e-300 ? 1.0/sig[i] : 0.0;
    for (int k = 0; k < 3; ++k) {
      double u = H[k][0]*Vs[0][i] + H[k][1]*Vs[1][i] + H[k][2]*Vs[2][i];
      U[k][i] = u*inv;
    }
  }
  if (sig[2] <= 1e-9*sig[0]) {
    U[0][2] = U[1][0]*U[2][1] - U[2][0]*U[1][1];
    U[1][2] = U[2][0]*U[0][1] - U[0][0]*U[2][1];
    U[2][2] = U[0][0]*U[1][1] - U[1][0]*U[0][1];
  }
  double detH = H[0][0]*(H[1][1]*H[2][2]-H[1][2]*H[2][1])
              - H[0][1]*(H[1][0]*H[2][2]-H[1][2]*H[2][0])
              + H[0][2]*(H[1][0]*H[2][1]-H[1][1]*H[2][0]);
  double s3[3] = {1.0, 1.0, detH > 0.0 ? 1.0 : -1.0};
  double R[3][3];
  for (int d = 0; d < 3; ++d)
    for (int e = 0; e < 3; ++e) {
      double s = 0.0;
      for (int i = 0; i < 3; ++i) s += s3[i]*Vs[d][i]*U[e][i];
      R[d][e] = s;
    }
  double tr[3];
  for (int d = 0; d < 3; ++d)
    tr[d] = cbd[b*3+d] - (R[d][0]*cad[b*3+0] + R[d][1]*cad[b*3+1] + R[d][2]*cad[b*3+2]);
  for (int d = 0; d < 3; ++d)
    for (int e = 0; e < 3; ++e)
      out[O_ROT + b*9 + d*3 + e] = (float)R[d][e];
  for (int d = 0; d < 3; ++d)
    out[O_TR + b*3 + d] = (float)tr[d];
}

__global__ void kfail(float* out, float v) { out[0] = v; }

extern "C" void kernel_launch(void* const* d_in, const int* in_sizes, int n_in,
                              void* d_out, int out_size, void* d_ws, size_t ws_size,
                              hipStream_t stream) {
  float* out = (float*)d_out;
  (void)out_size;

  /* input-order auto-detect: dict (src,tgt,src_emb,tgt_emb) vs alphabetical */
  int i_tgt = 1, i_semb = 2;
  if (n_in == 4 && in_sizes[1] == B_*C_*N_) { i_semb = 1; i_tgt = 2; }
  const float* src  = (const float*)d_in[0];
  const float* tgt  = (const float*)d_in[i_tgt];
  const float* semb = (const float*)d_in[i_semb];
  const float* temb = (const float*)d_in[3];

  char* w = (char*)d_ws;
  auto alloc = [&](size_t bytes) { char* p = w; w += (bytes + 255)/256*256; return p; };
  float*  sqpartA = (float*)alloc((size_t)CS_*B_*N_*4);
  float*  sqpartB = (float*)alloc((size_t)CS_*B_*N_*4);
  float*  xx      = (float*)alloc((size_t)B_*N_*4);
  float*  yy      = (float*)alloc((size_t)B_*M_*4);
  float*  rowZf   = (float*)alloc((size_t)B_*N_*4);
  float*  rowSmax = (float*)alloc((size_t)B_*N_*4);
  float*  colZ0f  = (float*)alloc((size_t)B_*M_*4);
  float*  rowps   = (float*)alloc((size_t)16*B_*N_*4);   /* partial-major [bm][b][n] */
  float*  rowpm   = (float*)alloc((size_t)16*B_*N_*4);
  float*  colps   = (float*)alloc((size_t)16*B_*M_*4);   /* [bn][b][m] */
  double* colSp   = (double*)alloc((size_t)32*B_*M_*8);  /* [rc][b][m] */
  double* rowSp   = (double*)alloc((size_t)16*B_*N_*8);  /* [cc][b][n] */
  double* col_sum = (double*)alloc((size_t)B_*M_*8);
  double* row_sum = (double*)alloc((size_t)B_*N_*8);
  double* kth_c   = (double*)alloc((size_t)B_*8);
  double* kth_r   = (double*)alloc((size_t)B_*8);
  unsigned char* rowmask = (unsigned char*)alloc((size_t)B_*N_);
  unsigned char* colmask = (unsigned char*)alloc((size_t)B_*M_);
  float*  vsi     = (float*)alloc((size_t)B_*N_*4);
  float*  srcw    = (float*)alloc((size_t)B_*N_*4);
  float*  sumvsi  = (float*)alloc((size_t)B_*4);
  float*  corrf   = (float*)alloc((size_t)B_*3*N_*4);
  double* covd = (double*)alloc((size_t)B_*9*8);
  double* cad  = (double*)alloc((size_t)B_*3*8);
  double* cbd  = (double*)alloc((size_t)B_*3*8);
  /* split-bf16 operand arrays [B][pos][C] */
  unsigned short* Ahg = (unsigned short*)alloc((size_t)B_*N_*C_*2);
  unsigned short* Alg = (unsigned short*)alloc((size_t)B_*N_*C_*2);
  unsigned short* Bhg = (unsigned short*)alloc((size_t)B_*M_*C_*2);
  unsigned short* Blg = (unsigned short*)alloc((size_t)B_*M_*C_*2);

  size_t used = (size_t)(w - (char*)d_ws);
  size_t rem = ws_size > used ? ws_size - used : 0;
  size_t oneE = (size_t)N_*M_*sizeof(float);
  int bc = (int)(rem / oneE);
  if (bc < 1) { kfail<<<1, 1, 0, stream>>>(out, 32768.f); return; }
  if (bc > B_) bc = B_;
  float* E = (float*)w;

  /* split + transpose both embeddings (fused sum-of-squares partials) */
  ksplit<<<dim3(N_/64, C_/64, 2*B_), 256, 0, stream>>>(semb, temb, Ahg, Alg, Bhg, Blg,
                                                       sqpartA, sqpartB);
  ksqcomb<<<dim3((B_*N_)/256, 2), 256, 0, stream>>>(sqpartA, sqpartB, xx, yy);

  for (int b0 = 0; b0 < B_; b0 += bc) {
    int cur = (B_ - b0 < bc) ? (B_ - b0) : bc;
    kgemm_mfma<<<dim3(N_/128, M_/128, cur), 256, 0, stream>>>(Ahg, Alg, Bhg, Blg,
                                                              xx, yy, E, rowps, rowpm, colps, b0);
    kstatcomb<<<dim3(cur*N_/256, 2), 256, 0, stream>>>(rowps, rowpm, colps,
                                                       rowZf, rowSmax, colZ0f, b0);
    kcross   <<<dim3(N_/64, M_/128, cur), 256, 0, stream>>>(E, rowZf, colZ0f, colSp, rowSp, b0);
    kcombab  <<<dim3(cur*M_/256, 2), 256, 0, stream>>>(colSp, rowSp, col_sum, row_sum, b0);
    kkth     <<<dim3(8, cur, 2), 256, 0, stream>>>(col_sum, row_sum, kth_c, kth_r, b0);
    kmask    <<<dim3(cur*8, 2), 256, 0, stream>>>(col_sum, row_sum, kth_c, kth_r,
                                                  colmask, rowmask, out, b0);
    kwcorr   <<<cur*N_, 256, 0, stream>>>(E, rowZf, rowSmax, rowmask, colmask, tgt,
                                          vsi, corrf, out + O_CORR, b0);
  }

  ksumvsi <<<B_, 256, 0, stream>>>(vsi, sumvsi);
  kweights<<<(B_*N_+255)/256, 256, 0, stream>>>(vsi, sumvsi, srcw, out + O_W);
  kcov    <<<B_, 256, 0, stream>>>(srcw, src, corrf, covd, cad, cbd);
  ksvd    <<<1, 64, 0, stream>>>(covd, cad, cbd, out);
}

// Round 17
// 308.444 us; speedup vs baseline: 1.8022x; 1.0049x over previous
//
#include <hip/hip_runtime.h>
#include <math.h>

#define B_ 8
#define C_ 512
#define N_ 2048
#define M_ 2048
#define KSEL 614          /* int(2048*0.3) */
#define EPS_ 1e-5f
#define CS_ 8             /* c-chunks (C/64) for sq partials */

#define O_CORR 0
#define O_W    (B_*3*N_)          /* 49152 */
#define O_MSRC (O_W + B_*N_)      /* 65536 */
#define O_MTGT (O_MSRC + B_*N_)   /* 81920 */
#define O_ROT  (O_MTGT + B_*M_)   /* 98304 */
#define O_TR   (O_ROT + B_*9)     /* 98376 */

typedef short bf16x8 __attribute__((ext_vector_type(8)));
typedef float f32x4 __attribute__((ext_vector_type(4)));

__device__ inline unsigned short f2bf(float f){
  unsigned u = __float_as_uint(f);
  return (unsigned short)((u + 0x7FFFu + ((u >> 16) & 1u)) >> 16);
}
__device__ inline float bf2f(unsigned short h){
  return __uint_as_float(((unsigned)h) << 16);
}

__device__ inline double blk_sumd(double v, double* sh){
  int t = threadIdx.x;
  sh[t] = v; __syncthreads();
  for (int s = 128; s > 0; s >>= 1) { if (t < s) sh[t] += sh[t+s]; __syncthreads(); }
  double r = sh[0]; __syncthreads(); return r;
}

/* ---- combine sq partials -> xx/yy (y selects A/B side) ---- */
__global__ __launch_bounds__(256) void ksqcomb(const float* __restrict__ partA,
                                               const float* __restrict__ partB,
                                               float* __restrict__ xx,
                                               float* __restrict__ yy)
{
  int i = blockIdx.x*256 + threadIdx.x;
  const float* part = blockIdx.y ? partB : partA;
  float* out = blockIdx.y ? yy : xx;
  float s = 0.f;
  for (int cs = 0; cs < CS_; ++cs) s += part[(size_t)cs*B_*N_ + i];
  out[i] = s;
}

/* ---- split f32 [B][C][P] -> hi/lo bf16 [B][P][C] + fused sum-of-squares
        partials; z selects src_emb vs tgt_emb ---- */
__global__ __launch_bounds__(256) void ksplit(const float* __restrict__ XA,
                                              const float* __restrict__ XB,
                                              unsigned short* __restrict__ XhA,
                                              unsigned short* __restrict__ XlA,
                                              unsigned short* __restrict__ XhB,
                                              unsigned short* __restrict__ XlB,
                                              float* __restrict__ sqpartA,
                                              float* __restrict__ sqpartB)
{
  __shared__ float tile[64][65];  /* [p][c] */
  int p0 = blockIdx.x*64, c0 = blockIdx.y*64;
  int zb = blockIdx.z;
  int b = zb & (B_-1);
  int side = zb >> 3;
  const float* X = side ? XB : XA;
  unsigned short* Xh = side ? XhB : XhA;
  unsigned short* Xl = side ? XlB : XlA;
  float* sqpart = side ? sqpartB : sqpartA;
  int cs = blockIdx.y;
  int t = threadIdx.x;
  const float* base = X + ((size_t)b*C_ + c0)*N_ + p0;
  int px = (t & 15)*4, cy = t >> 4;
#pragma unroll
  for (int i = 0; i < 4; ++i) {
    int c = cy + i*16;
    float4 v = *(const float4*)(base + (size_t)c*N_ + px);
    tile[px+0][c] = v.x; tile[px+1][c] = v.y; tile[px+2][c] = v.z; tile[px+3][c] = v.w;
  }
  __syncthreads();
  int cx = (t & 15)*4, py = t >> 4;
  unsigned short* oh = Xh + ((size_t)b*N_ + p0)*C_ + c0;
  unsigned short* ol = Xl + ((size_t)b*N_ + p0)*C_ + c0;
#pragma unroll
  for (int i = 0; i < 4; ++i) {
    int p = py + i*16;
    float v0 = tile[p][cx], v1 = tile[p][cx+1], v2 = tile[p][cx+2], v3 = tile[p][cx+3];
    ushort4 h, l;
    h.x = f2bf(v0); l.x = f2bf(v0 - bf2f(h.x));
    h.y = f2bf(v1); l.y = f2bf(v1 - bf2f(h.y));
    h.z = f2bf(v2); l.z = f2bf(v2 - bf2f(h.z));
    h.w = f2bf(v3); l.w = f2bf(v3 - bf2f(h.w));
    *(ushort4*)(oh + (size_t)p*C_ + cx) = h;
    *(ushort4*)(ol + (size_t)p*C_ + cx) = l;
    float sqv = v0*v0 + v1*v1 + v2*v2 + v3*v3;
#pragma unroll
    for (int off = 1; off < 16; off <<= 1) sqv += __shfl_xor(sqv, off, 16);
    if ((t & 15) == 0) sqpart[((size_t)cs*B_ + b)*N_ + p0 + p] = sqv;
  }
}

/* ---- MFMA GEMM: E = exp(2*(Ah+Al)^T(Bh+Bl) - xx - yy), 3-term split-bf16.
        global_load_lds width-16, double-buffered, linear LDS dest with
        PRE-SWIZZLED global source (slot' = slot ^ ((row>>1)&3)); same XOR
        applied on ds_read -> max 2-way bank aliasing (free). Linear [128][32]
        ushort tiles (64B rows, 16B-aligned). XCD-aware tile swizzle.
        Epilogue fuses row/col stat partials. ---- */
__global__ __launch_bounds__(256, 1) void kgemm_mfma(
    const unsigned short* __restrict__ Ahg, const unsigned short* __restrict__ Alg,
    const unsigned short* __restrict__ Bhg, const unsigned short* __restrict__ Blg,
    const float* __restrict__ xx, const float* __restrict__ yy,
    float* __restrict__ E, float* __restrict__ rowps, float* __restrict__ rowpm,
    float* __restrict__ colps, int b_off)
{
  __shared__ unsigned short smem[2*4*128*32];   /* 65536 B: 2 bufs x 4 ops x 8KB */

  /* XCD swizzle (bijective permutation of the 16x16 tile grid) */
  int sflat = blockIdx.x + 16*blockIdx.y;     /* 0..255 */
  int xcd = sflat & 7, si = sflat >> 3;       /* si in 0..31 */
  int ka = xcd >> 1, kb = xcd & 1;
  int bn = ka*4 + (si & 3);
  int bm = kb*8 + (si >> 2);
  int bz = blockIdx.z;
  int b = b_off + bz;
  int t = threadIdx.x;
  int lane = t & 63, w = t >> 6;
  int wr = (w >> 1)*64, wc = (w & 1)*64;
  int lrow = lane & 15, lgr = (lane >> 4)*8;
  size_t abase = ((size_t)b*N_ + (size_t)bn*128)*C_;
  size_t bbase = ((size_t)b*M_ + (size_t)bm*128)*C_;
  int lr4 = lane >> 2;          /* 0..15: row within 16-row chunk */
  /* pre-swizzled global source column: slot XOR'd by ((row>>1)&3); for staging
     rows, (row>>1)&3 == (lr4>>1)&3 since rblk*16 contributes 0 mod 4 after >>1 */
  int lc4s = ((lane & 3)*8) ^ (((lr4 >> 1) & 3) << 3);
  /* fragment-read swizzle: (row>>1)&3 == (lrow>>1)&3 (wr, f*16 are mult of 16) */
  int lgr_sw = lgr ^ (((lrow >> 1) & 3) << 3);

  f32x4 acc[4][4];
#pragma unroll
  for (int i = 0; i < 4; ++i)
#pragma unroll
    for (int j = 0; j < 4; ++j) acc[i][j] = (f32x4){0.f, 0.f, 0.f, 0.f};

  /* issue async global->LDS for one K-slice into buffer bufk.
     LDS dest is wave-uniform base; HW writes lane l at base + l*16B (linear).
     Global source column is pre-swizzled so that a swizzled ds_read recovers
     the original data. */
#define ISSUE(bufk, K0) do { \
    unsigned short* bb0 = smem + (bufk)*16384; \
    _Pragma("unroll") \
    for (int q = 0; q < 2; ++q) { \
      int rblk = w*2 + q; \
      size_t roff = (size_t)(rblk*16 + lr4)*C_ + (K0) + lc4s; \
      unsigned short* ldsb = bb0 + rblk*512; \
      __builtin_amdgcn_global_load_lds((const void*)(Ahg + abase + roff), (void*)(ldsb),         16, 0, 0); \
      __builtin_amdgcn_global_load_lds((const void*)(Alg + abase + roff), (void*)(ldsb + 4096),  16, 0, 0); \
      __builtin_amdgcn_global_load_lds((const void*)(Bhg + bbase + roff), (void*)(ldsb + 8192),  16, 0, 0); \
      __builtin_amdgcn_global_load_lds((const void*)(Blg + bbase + roff), (void*)(ldsb + 12288), 16, 0, 0); \
    } \
  } while (0)

  ISSUE(0, 0);
  int cur = 0;
  for (int ks = 0; ks < 16; ++ks) {
    __syncthreads();                  /* drains this wave's gload vmcnt + syncs */
    if (ks < 15) { int k0n = (ks+1)*32; ISSUE(cur^1, k0n); }
    unsigned short* bb = smem + cur*16384;
    unsigned short* Ahs = bb;
    unsigned short* Als = bb + 4096;
    unsigned short* Bhs = bb + 8192;
    unsigned short* Bls = bb + 12288;
    bf16x8 ah[4], al[4], bh[4], bl[4];
#pragma unroll
    for (int f = 0; f < 4; ++f) {
      int ra = (wr + f*16 + lrow)*32 + lgr_sw;
      int rb = (wc + f*16 + lrow)*32 + lgr_sw;
      ah[f] = *(const bf16x8*)&Ahs[ra];
      al[f] = *(const bf16x8*)&Als[ra];
      bh[f] = *(const bf16x8*)&Bhs[rb];
      bl[f] = *(const bf16x8*)&Bls[rb];
    }
#pragma unroll
    for (int fi = 0; fi < 4; ++fi)
#pragma unroll
      for (int fj = 0; fj < 4; ++fj) {
        acc[fi][fj] = __builtin_amdgcn_mfma_f32_16x16x32_bf16(ah[fi], bh[fj], acc[fi][fj], 0, 0, 0);
        acc[fi][fj] = __builtin_amdgcn_mfma_f32_16x16x32_bf16(ah[fi], bl[fj], acc[fi][fj], 0, 0, 0);
        acc[fi][fj] = __builtin_amdgcn_mfma_f32_16x16x32_bf16(al[fi], bh[fj], acc[fi][fj], 0, 0, 0);
      }
    cur ^= 1;
  }
#undef ISSUE

  /* ---- two-pass epilogue (64x132 f32 LDS tile = 33792B <= 65536B) ---- */
  float* eps = (float*)smem;
  float* Eb = E + (size_t)bz*N_*M_;
  int lg = lane >> 4;                    /* 0..3 */
  int row0 = t >> 5;                     /* 0..7 */
  int c4 = (t & 31)*4;                   /* 0..124 */
  const float* yb = yy + b*M_ + bm*128;
  float4 vy = *(const float4*)(yb + c4);
  float ca0 = 0.f, ca1 = 0.f, ca2 = 0.f, ca3 = 0.f;   /* column partials */
#pragma unroll
  for (int pass = 0; pass < 2; ++pass) {
    __syncthreads();
    if ((w >> 1) == pass) {
#pragma unroll
      for (int fi = 0; fi < 4; ++fi) {
        int nl = lg*4 + fi*16;
#pragma unroll
        for (int fj = 0; fj < 4; ++fj) {
          int ml = wc + (lane & 15) + fj*16;
#pragma unroll
          for (int r = 0; r < 4; ++r)
            eps[(nl + r)*132 + ml] = acc[fi][fj][r];
        }
      }
    }
    __syncthreads();
#pragma unroll
    for (int it = 0; it < 8; ++it) {
      int row = it*8 + row0;
      int gn = bn*128 + pass*64 + row;
      float xv = xx[b*N_ + gn];
      float4 s = *(float4*)&eps[row*132 + c4];
      float4 o;
      o.x = expf(2.f*s.x - xv - vy.x);
      o.y = expf(2.f*s.y - xv - vy.y);
      o.z = expf(2.f*s.z - xv - vy.z);
      o.w = expf(2.f*s.w - xv - vy.w);
      *(float4*)(Eb + (size_t)gn*M_ + bm*128 + c4) = o;
      float rs = o.x + o.y + o.z + o.w;
      float rm2 = fmaxf(fmaxf(o.x, o.y), fmaxf(o.z, o.w));
      ca0 += o.x; ca1 += o.y; ca2 += o.z; ca3 += o.w;
#pragma unroll
      for (int off = 16; off > 0; off >>= 1) {
        rs += __shfl_xor(rs, off, 32);
        rm2 = fmaxf(rm2, __shfl_xor(rm2, off, 32));
      }
      if ((t & 31) == 0) {
        rowps[(size_t)bm*B_*N_ + (size_t)b*N_ + gn] = rs;
        rowpm[(size_t)bm*B_*N_ + (size_t)b*N_ + gn] = rm2;
      }
    }
  }
  __syncthreads();
  float* colsh = (float*)smem;           /* [8][128] */
  colsh[row0*128 + c4+0] = ca0;
  colsh[row0*128 + c4+1] = ca1;
  colsh[row0*128 + c4+2] = ca2;
  colsh[row0*128 + c4+3] = ca3;
  __syncthreads();
  if (t < 128) {
    float s = 0.f;
#pragma unroll
    for (int g = 0; g < 8; ++g) s += colsh[g*128 + t];
    colps[(size_t)bn*B_*M_ + (size_t)b*M_ + bm*128 + t] = s;
  }
}

/* ---- fused: y==0 -> rowZ/rowSmax from row partials; y==1 -> colZ0 ---- */
__global__ __launch_bounds__(256) void kstatcomb(
    const float* __restrict__ rowps, const float* __restrict__ rowpm,
    const float* __restrict__ colps,
    float* __restrict__ rowZf, float* __restrict__ rowSmax,
    float* __restrict__ colZ0f, int b_off)
{
  int i = blockIdx.x*256 + threadIdx.x;
  size_t gi = (size_t)b_off*N_ + i;
  if (blockIdx.y == 0) {
    double s = 0.0; float mx = 0.f;
#pragma unroll
    for (int k = 0; k < 16; ++k) {
      s += (double)rowps[(size_t)k*B_*N_ + gi];
      mx = fmaxf(mx, rowpm[(size_t)k*B_*N_ + gi]);
    }
    float zf = (float)s;
    rowZf[gi] = zf;
    rowSmax[gi] = mx * (1.f / zf);  /* same RN(1/zf) recomputed in kwcorr */
  } else {
    double s = 0.0;
#pragma unroll
    for (int k = 0; k < 16; ++k) s += (double)colps[(size_t)k*B_*M_ + gi];
    colZ0f[gi] = (float)s;
  }
}

/* ---- fused cross pass: one E read -> colSp (sum_n E/rowZ) AND rowSp
        (sum_m E/colZ0), f64 partials; reciprocals precomputed in LDS. ---- */
__global__ __launch_bounds__(256) void kcross(const float* __restrict__ E,
                                              const float* __restrict__ rowZf,
                                              const float* __restrict__ colZ0f,
                                              double* __restrict__ colSp,
                                              double* __restrict__ rowSp, int b_off)
{
  __shared__ float tile[64*129];   /* 33024 B */
  __shared__ double rzinv[64];
  __shared__ double czinv[128];
  __shared__ double shd[256];
  int rc = blockIdx.x, cc = blockIdx.y, bz = blockIdx.z;
  int b = b_off + bz;
  int r0 = rc*64, c0 = cc*128;
  int t = threadIdx.x;
  const float* Eb = E + (size_t)bz*N_*M_;
  {
    int rr = t >> 5, cq = (t & 31)*4;
#pragma unroll
    for (int it = 0; it < 8; ++it) {
      int row = it*8 + rr;
      float4 v = *(const float4*)(Eb + (size_t)(r0+row)*M_ + c0 + cq);
      tile[row*129 + cq+0] = v.x;
      tile[row*129 + cq+1] = v.y;
      tile[row*129 + cq+2] = v.z;
      tile[row*129 + cq+3] = v.w;
    }
  }
  if (t < 64) rzinv[t] = 1.0 / (double)rowZf[(size_t)b*N_ + r0 + t];
  if (t >= 128) czinv[t-128] = 1.0 / (double)colZ0f[(size_t)b*M_ + c0 + (t-128)];
  __syncthreads();
  {
    int j = t & 127, rg = t >> 7;
    double a = 0.0;
    for (int rr = rg*32; rr < rg*32 + 32; ++rr)
      a += (double)tile[rr*129 + j] * rzinv[rr];
    shd[rg*128 + j] = a;
  }
  __syncthreads();
  if (t < 128)
    colSp[(size_t)rc*B_*M_ + (size_t)b*M_ + c0 + t] = shd[t] + shd[128 + t];
  __syncthreads();
  {
    int r = t & 63, h = t >> 6;
    double a = 0.0;
    for (int j = h*32; j < h*32 + 32; ++j)
      a += (double)tile[r*129 + j] * czinv[j];
    shd[h*64 + r] = a;
  }
  __syncthreads();
  if (t < 64)
    rowSp[(size_t)cc*B_*N_ + (size_t)b*N_ + r0 + t] = shd[t] + shd[64+t] + shd[128+t] + shd[192+t];
}

/* ---- fused: y==0 -> col_sum (32 partials); y==1 -> row_sum (16 partials) ---- */
__global__ __launch_bounds__(256) void kcombab(const double* __restrict__ colSp,
                                               const double* __restrict__ rowSp,
                                               double* __restrict__ col_sum,
                                               double* __restrict__ row_sum, int b_off)
{
  int i = blockIdx.x*256 + threadIdx.x;
  if (blockIdx.y == 0) {
    size_t gi = (size_t)b_off*M_ + i;
    double s = 0.0;
    for (int k = 0; k < 32; ++k) s += colSp[(size_t)k*B_*M_ + gi];
    col_sum[gi] = s;
  } else {
    size_t gi = (size_t)b_off*N_ + i;
    double s = 0.0;
    for (int k = 0; k < 16; ++k) s += rowSp[(size_t)k*B_*N_ + gi];
    row_sum[gi] = s;
  }
}

/* ---- exact K-th smallest via rank count; z selects col/row side ---- */
__global__ __launch_bounds__(256) void kkth(const double* __restrict__ col_sum,
                                            const double* __restrict__ row_sum,
                                            double* __restrict__ kth_c,
                                            double* __restrict__ kth_r, int b_off)
{
  __shared__ double sv[2048];
  int b = b_off + blockIdx.y;
  const double* v = (blockIdx.z == 0 ? col_sum : row_sum) + b*2048;
  double* kth = (blockIdx.z == 0 ? kth_c : kth_r);
  int t = threadIdx.x;
  for (int i = t; i < 2048; i += 256) sv[i] = v[i];
  __syncthreads();
  int i = blockIdx.x*256 + t;
  double vi = sv[i];
  int lt = 0, le = 0;
  for (int j = 0; j < 2048; ++j) { double vj = sv[j]; lt += (vj < vi); le += (vj <= vi); }
  if (lt < KSEL && KSEL <= le) kth[b] = vi;
}

/* ---- masks; y selects col/row side ---- */
__global__ __launch_bounds__(256) void kmask(const double* __restrict__ col_sum,
                                             const double* __restrict__ row_sum,
                                             const double* __restrict__ kth_c,
                                             const double* __restrict__ kth_r,
                                             unsigned char* __restrict__ colmask,
                                             unsigned char* __restrict__ rowmask,
                                             float* __restrict__ out, int b_off)
{
  int side = blockIdx.y;
  const double* vals = side ? row_sum : col_sum;
  const double* kth = side ? kth_r : kth_c;
  unsigned char* m8 = side ? rowmask : colmask;
  float* mout = out + (side ? O_MSRC : O_MTGT);
  int i = blockIdx.x*256 + threadIdx.x;
  int b = b_off + i/2048, j = i & 2047;
  bool m = vals[b*2048 + j] < kth[b];
  m8[b*2048 + j] = m ? 1 : 0;
  mout[b*2048 + j] = m ? 1.f : 0.f;
}

/* ---- sparse renorm + vsi + src_corr: register-cached row (8 vals/thread),
        wave-shuffle reductions, reciprocal multiplies ---- */
__global__ __launch_bounds__(256) void kwcorr(
    const float* __restrict__ E, const float* __restrict__ rowZf,
    const float* __restrict__ rowSmax,
    const unsigned char* __restrict__ rowmask, const unsigned char* __restrict__ colmask,
    const float* __restrict__ tgt, float* __restrict__ vsi,
    float* __restrict__ corrf, float* __restrict__ corr_out, int b_off)
{
  __shared__ float shred[20];
  int r = blockIdx.x, t = threadIdx.x;
  int bz = r / N_, n = r % N_;
  int b = b_off + bz;
  const float* row = E + (size_t)bz*N_*M_ + (size_t)n*M_;
  float rinv = 1.f / rowZf[b*N_+n];       /* bit-identical to kstatcomb's rinv */
  int lane = t & 63, w = t >> 6;
  float rmax = rowSmax[b*N_+n];
  int rm = rowmask[b*N_+n];
  const unsigned char* cm = colmask + b*M_;
  float v[8];
  unsigned kp = 0;
  float s = 0.f;
#pragma unroll
  for (int il = 0; il < 8; ++il) {
    int m = t + il*256;
    float vv = row[m] * rinv;
    v[il] = vv;
    bool keep = rm || cm[m] || (vv >= rmax);
    kp |= (keep ? 1u : 0u) << il;
    if (keep) s += vv;
  }
#pragma unroll
  for (int off = 32; off; off >>= 1) s += __shfl_xor(s, off, 64);
  if (!lane) shred[w] = s;
  __syncthreads();
  s = shred[0] + shred[1] + shred[2] + shred[3];
  float d = (s < EPS_) ? EPS_ : s;
  float dinv = 1.f / d;
  const float* t0 = tgt + (size_t)b*3*M_;
  float vs = 0.f, a0 = 0.f, a1 = 0.f, a2 = 0.f;
#pragma unroll
  for (int il = 0; il < 8; ++il) {
    int m = t + il*256;
    float wv = (kp >> il & 1u) ? v[il]*dinv : 0.f;
    vs += wv;
    a0 += wv * t0[m];
    a1 += wv * t0[M_+m];
    a2 += wv * t0[2*M_+m];
  }
#pragma unroll
  for (int off = 32; off; off >>= 1) {
    vs += __shfl_xor(vs, off, 64);
    a0 += __shfl_xor(a0, off, 64);
    a1 += __shfl_xor(a1, off, 64);
    a2 += __shfl_xor(a2, off, 64);
  }
  if (!lane) {
    shred[4 + w] = vs; shred[8 + w] = a0; shred[12 + w] = a1; shred[16 + w] = a2;
  }
  __syncthreads();
  if (!t) {
    float vsT = shred[4]+shred[5]+shred[6]+shred[7];
    float a0T = shred[8]+shred[9]+shred[10]+shred[11];
    float a1T = shred[12]+shred[13]+shred[14]+shred[15];
    float a2T = shred[16]+shred[17]+shred[18]+shred[19];
    vsi[b*N_+n] = rm ? 0.f : vsT;
    size_t o = (size_t)b*3*N_ + n;
    corrf[o] = a0T; corrf[o+N_] = a1T; corrf[o+2*N_] = a2T;
    corr_out[o]      = a0T;
    corr_out[o+N_]   = a1T;
    corr_out[o+2*N_] = a2T;
  }
}

__global__ __launch_bounds__(256) void ksumvsi(const float* __restrict__ vsi,
                                               float* __restrict__ out)
{
  __shared__ double shd[256];
  int b = blockIdx.x;
  double s = 0.0;
  for (int n = threadIdx.x; n < N_; n += 256) s += (double)vsi[b*N_+n];
  s = blk_sumd(s, shd);
  if (!threadIdx.x) out[b] = (float)s;
}

__global__ __launch_bounds__(256) void kweights(const float* __restrict__ vsi,
                                                const float* __restrict__ sumvsi,
                                                float* __restrict__ srcw,
                                                float* __restrict__ wout)
{
  int i = blockIdx.x*256 + threadIdx.x;
  if (i >= B_*N_) return;
  int b = i / N_;
  float w = vsi[i] / sumvsi[b];
  srcw[i] = w;
  wout[i] = w;
}

__global__ __launch_bounds__(256) void kcov(const float* __restrict__ srcw,
                                            const float* __restrict__ src,
                                            const float* __restrict__ corrf,
                                            double* covd, double* cad, double* cbd)
{
  __shared__ double sh[256];
  int b = blockIdx.x, t = threadIdx.x;
  const float* w = srcw + b*N_;
  const float* a = src  + (size_t)b*3*N_;
  const float* bb = corrf + (size_t)b*3*N_;
  double sw = 0.0;
  for (int n = t; n < N_; n += 256) sw += (double)w[n];
  sw = blk_sumd(sw, sh);
  double inv = 1.0/(sw + 1e-5);
  double p0=0,p1=0,p2=0,p3=0,p4=0,p5=0;
  for (int n = t; n < N_; n += 256) {
    double wn = (double)w[n]*inv;
    p0 += (double)a[n]*wn;      p1 += (double)a[N_+n]*wn;   p2 += (double)a[2*N_+n]*wn;
    p3 += (double)bb[n]*wn;     p4 += (double)bb[N_+n]*wn;  p5 += (double)bb[2*N_+n]*wn;
  }
  double ca0 = blk_sumd(p0, sh), ca1 = blk_sumd(p1, sh), ca2 = blk_sumd(p2, sh);
  double cb0 = blk_sumd(p3, sh), cb1 = blk_sumd(p4, sh), cb2 = blk_sumd(p5, sh);
  double c[9] = {0,0,0,0,0,0,0,0,0};
  for (int n = t; n < N_; n += 256) {
    double wn = (double)w[n]*inv;
    double a0 = (double)a[n]-ca0, a1d = (double)a[N_+n]-ca1, a2d = (double)a[2*N_+n]-ca2;
    double b0 = ((double)bb[n]-cb0)*wn, b1 = ((double)bb[N_+n]-cb1)*wn, b2 = ((double)bb[2*N_+n]-cb2)*wn;
    c[0]+=a0*b0; c[1]+=a0*b1; c[2]+=a0*b2;
    c[3]+=a1d*b0; c[4]+=a1d*b1; c[5]+=a1d*b2;
    c[6]+=a2d*b0; c[7]+=a2d*b1; c[8]+=a2d*b2;
  }
  for (int k = 0; k < 9; ++k) {
    double rr = blk_sumd(c[k], sh);
    if (!t) covd[b*9+k] = rr;
  }
  if (!t) {
    cad[b*3+0]=ca0; cad[b*3+1]=ca1; cad[b*3+2]=ca2;
    cbd[b*3+0]=cb0; cbd[b*3+1]=cb1; cbd[b*3+2]=cb2;
  }
}

/* ---- 3x3 Kabsch via Jacobi eigendecomposition of H^T H (f64) ---- */
__global__ void ksvd(const double* __restrict__ covd, const double* __restrict__ cad,
                     const double* __restrict__ cbd, float* out)
{
  int b = threadIdx.x;
  if (b >= B_) return;
  double H[3][3];
  for (int i = 0; i < 3; ++i) for (int j = 0; j < 3; ++j) H[i][j] = covd[b*9+i*3+j];
  double A[3][3];
  for (int i = 0; i < 3; ++i)
    for (int j = 0; j < 3; ++j) {
      double s = 0.0;
      for (int l = 0; l < 3; ++l) s += H[l][i]*H[l][j];
      A[i][j] = s;
    }
  double V[3][3] = {{1,0,0},{0,1,0},{0,0,1}};
  const int PP[3] = {0,0,1}, QQ[3] = {1,2,2};
  for (int sweep = 0; sweep < 24; ++sweep) {
    double off = fabs(A[0][1])+fabs(A[0][2])+fabs(A[1][2]);
    if (off < 1e-28) break;
    for (int r = 0; r < 3; ++r) {
      int p = PP[r], q = QQ[r];
      double apq = A[p][q];
      if (fabs(apq) < 1e-300) continue;
      double th = (A[q][q]-A[p][p])/(2.0*apq);
      double tt = (th >= 0.0 ? 1.0 : -1.0)/(fabs(th)+sqrt(th*th+1.0));
      double cc = 1.0/sqrt(tt*tt+1.0), ss = tt*cc;
      for (int k = 0; k < 3; ++k) {
        double akp = A[k][p], akq = A[k][q];
        A[k][p] = cc*akp - ss*akq; A[k][q] = ss*akp + cc*akq;
      }
      for (int k = 0; k < 3; ++k) {
        double apk = A[p][k], aqk = A[q][k];
        A[p][k] = cc*apk - ss*aqk; A[q][k] = ss*apk + cc*aqk;
      }
      for (int k = 0; k < 3; ++k) {
        double vkp = V[k][p], vkq = V[k][q];
        V[k][p] = cc*vkp - ss*vkq; V[k][q] = ss*vkp + cc*vkq;
      }
    }
  }
  double lam[3] = {A[0][0], A[1][1], A[2][2]};
  int idx[3] = {0,1,2};
  for (int i = 0; i < 2; ++i)
    for (int j = i+1; j < 3; ++j)
      if (lam[idx[j]] > lam[idx[i]]) { int tmp = idx[i]; idx[i] = idx[j]; idx[j] = tmp; }
  double Vs[3][3], sig[3];
  for (int i = 0; i < 3; ++i) {
    for (int k = 0; k < 3; ++k) Vs[k][i] = V[k][idx[i]];
    double l = lam[idx[i]];
    sig[i] = sqrt(l > 0.0 ? l : 0.0);
  }
  double U[3][3];
  for (int i = 0; i < 3; ++i) {
    double inv = sig[i] > 1e-300 ? 1.0/sig[i] : 0.0;
    for (int k = 0; k < 3; ++k) {
      double u = H[k][0]*Vs[0][i] + H[k][1]*Vs[1][i] + H[k][2]*Vs[2][i];
      U[k][i] = u*inv;
    }
  }
  if (sig[2] <= 1e-9*sig[0]) {
    U[0][2] = U[1][0]*U[2][1] - U[2][0]*U[1][1];
    U[1][2] = U[2][0]*U[0][1] - U[0][0]*U[2][1];
    U[2][2] = U[0][0]*U[1][1] - U[1][0]*U[0][1];
  }
  double detH = H[0][0]*(H[1][1]*H[2][2]-H[1][2]*H[2][1])
              - H[0][1]*(H[1][0]*H[2][2]-H[1][2]*H[2][0])
              + H[0][2]*(H[1][0]*H[2][1]-H[1][1]*H[2][0]);
  double s3[3] = {1.0, 1.0, detH > 0.0 ? 1.0 : -1.0};
  double R[3][3];
  for (int d = 0; d < 3; ++d)
    for (int e = 0; e < 3; ++e) {
      double s = 0.0;
      for (int i = 0; i < 3; ++i) s += s3[i]*Vs[d][i]*U[e][i];
      R[d][e] = s;
    }
  double tr[3];
  for (int d = 0; d < 3; ++d)
    tr[d] = cbd[b*3+d] - (R[d][0]*cad[b*3+0] + R[d][1]*cad[b*3+1] + R[d][2]*cad[b*3+2]);
  for (int d = 0; d < 3; ++d)
    for (int e = 0; e < 3; ++e)
      out[O_ROT + b*9 + d*3 + e] = (float)R[d][e];
  for (int d = 0; d < 3; ++d)
    out[O_TR + b*3 + d] = (float)tr[d];
}

__global__ void kfail(float* out, float v) { out[0] = v; }

extern "C" void kernel_launch(void* const* d_in, const int* in_sizes, int n_in,
                              void* d_out, int out_size, void* d_ws, size_t ws_size,
                              hipStream_t stream) {
  float* out = (float*)d_out;
  (void)out_size;

  /* input-order auto-detect: dict (src,tgt,src_emb,tgt_emb) vs alphabetical */
  int i_tgt = 1, i_semb = 2;
  if (n_in == 4 && in_sizes[1] == B_*C_*N_) { i_semb = 1; i_tgt = 2; }
  const float* src  = (const float*)d_in[0];
  const float* tgt  = (const float*)d_in[i_tgt];
  const float* semb = (const float*)d_in[i_semb];
  const float* temb = (const float*)d_in[3];

  char* w = (char*)d_ws;
  auto alloc = [&](size_t bytes) { char* p = w; w += (bytes + 255)/256*256; return p; };
  float*  sqpartA = (float*)alloc((size_t)CS_*B_*N_*4);
  float*  sqpartB = (float*)alloc((size_t)CS_*B_*N_*4);
  float*  xx      = (float*)alloc((size_t)B_*N_*4);
  float*  yy      = (float*)alloc((size_t)B_*M_*4);
  float*  rowZf   = (float*)alloc((size_t)B_*N_*4);
  float*  rowSmax = (float*)alloc((size_t)B_*N_*4);
  float*  colZ0f  = (float*)alloc((size_t)B_*M_*4);
  float*  rowps   = (float*)alloc((size_t)16*B_*N_*4);   /* partial-major [bm][b][n] */
  float*  rowpm   = (float*)alloc((size_t)16*B_*N_*4);
  float*  colps   = (float*)alloc((size_t)16*B_*M_*4);   /* [bn][b][m] */
  double* colSp   = (double*)alloc((size_t)32*B_*M_*8);  /* [rc][b][m] */
  double* rowSp   = (double*)alloc((size_t)16*B_*N_*8);  /* [cc][b][n] */
  double* col_sum = (double*)alloc((size_t)B_*M_*8);
  double* row_sum = (double*)alloc((size_t)B_*N_*8);
  double* kth_c   = (double*)alloc((size_t)B_*8);
  double* kth_r   = (double*)alloc((size_t)B_*8);
  unsigned char* rowmask = (unsigned char*)alloc((size_t)B_*N_);
  unsigned char* colmask = (unsigned char*)alloc((size_t)B_*M_);
  float*  vsi     = (float*)alloc((size_t)B_*N_*4);
  float*  srcw    = (float*)alloc((size_t)B_*N_*4);
  float*  sumvsi  = (float*)alloc((size_t)B_*4);
  float*  corrf   = (float*)alloc((size_t)B_*3*N_*4);
  double* covd = (double*)alloc((size_t)B_*9*8);
  double* cad  = (double*)alloc((size_t)B_*3*8);
  double* cbd  = (double*)alloc((size_t)B_*3*8);
  /* split-bf16 operand arrays [B][pos][C] */
  unsigned short* Ahg = (unsigned short*)alloc((size_t)B_*N_*C_*2);
  unsigned short* Alg = (unsigned short*)alloc((size_t)B_*N_*C_*2);
  unsigned short* Bhg = (unsigned short*)alloc((size_t)B_*M_*C_*2);
  unsigned short* Blg = (unsigned short*)alloc((size_t)B_*M_*C_*2);

  size_t used = (size_t)(w - (char*)d_ws);
  size_t rem = ws_size > used ? ws_size - used : 0;
  size_t oneE = (size_t)N_*M_*sizeof(float);
  int bc = (int)(rem / oneE);
  if (bc < 1) { kfail<<<1, 1, 0, stream>>>(out, 32768.f); return; }
  if (bc > B_) bc = B_;
  float* E = (float*)w;

  /* split + transpose both embeddings (fused sum-of-squares partials) */
  ksplit<<<dim3(N_/64, C_/64, 2*B_), 256, 0, stream>>>(semb, temb, Ahg, Alg, Bhg, Blg,
                                                       sqpartA, sqpartB);
  ksqcomb<<<dim3((B_*N_)/256, 2), 256, 0, stream>>>(sqpartA, sqpartB, xx, yy);

  for (int b0 = 0; b0 < B_; b0 += bc) {
    int cur = (B_ - b0 < bc) ? (B_ - b0) : bc;
    kgemm_mfma<<<dim3(N_/128, M_/128, cur), 256, 0, stream>>>(Ahg, Alg, Bhg, Blg,
                                                              xx, yy, E, rowps, rowpm, colps, b0);
    kstatcomb<<<dim3(cur*N_/256, 2), 256, 0, stream>>>(rowps, rowpm, colps,
                                                       rowZf, rowSmax, colZ0f, b0);
    kcross   <<<dim3(N_/64, M_/128, cur), 256, 0, stream>>>(E, rowZf, colZ0f, colSp, rowSp, b0);
    kcombab  <<<dim3(cur*M_/256, 2), 256, 0, stream>>>(colSp, rowSp, col_sum, row_sum, b0);
    kkth     <<<dim3(8, cur, 2), 256, 0, stream>>>(col_sum, row_sum, kth_c, kth_r, b0);
    kmask    <<<dim3(cur*8, 2), 256, 0, stream>>>(col_sum, row_sum, kth_c, kth_r,
                                                  colmask, rowmask, out, b0);
    kwcorr   <<<cur*N_, 256, 0, stream>>>(E, rowZf, rowSmax, rowmask, colmask, tgt,
                                          vsi, corrf, out + O_CORR, b0);
  }

  ksumvsi <<<B_, 256, 0, stream>>>(vsi, sumvsi);
  kweights<<<(B_*N_+255)/256, 256, 0, stream>>>(vsi, sumvsi, srcw, out + O_W);
  kcov    <<<B_, 256, 0, stream>>>(srcw, src, corrf, covd, cad, cbd);
  ksvd    <<<1, 64, 0, stream>>>(covd, cad, cbd, out);
}

// Round 18
// 291.671 us; speedup vs baseline: 1.9059x; 1.0575x over previous
//
#include <hip/hip_runtime.h>
#include <math.h>

#define B_ 8
#define C_ 512
#define N_ 2048
#define M_ 2048
#define KSEL 614          /* int(2048*0.3) */
#define EPS_ 1e-5f
#define CS_ 8             /* c-chunks (C/64) for sq partials */

#define O_CORR 0
#define O_W    (B_*3*N_)          /* 49152 */
#define O_MSRC (O_W + B_*N_)      /* 65536 */
#define O_MTGT (O_MSRC + B_*N_)   /* 81920 */
#define O_ROT  (O_MTGT + B_*M_)   /* 98304 */
#define O_TR   (O_ROT + B_*9)     /* 98376 */

typedef short bf16x8 __attribute__((ext_vector_type(8)));
typedef float f32x4 __attribute__((ext_vector_type(4)));

__device__ inline unsigned short f2bf(float f){
  unsigned u = __float_as_uint(f);
  return (unsigned short)((u + 0x7FFFu + ((u >> 16) & 1u)) >> 16);
}
__device__ inline float bf2f(unsigned short h){
  return __uint_as_float(((unsigned)h) << 16);
}

__device__ inline double blk_sumd(double v, double* sh){
  int t = threadIdx.x;
  sh[t] = v; __syncthreads();
  for (int s = 128; s > 0; s >>= 1) { if (t < s) sh[t] += sh[t+s]; __syncthreads(); }
  double r = sh[0]; __syncthreads(); return r;
}

/* ---- combine sq partials -> xx/yy (y selects A/B side) ---- */
__global__ __launch_bounds__(256) void ksqcomb(const float* __restrict__ partA,
                                               const float* __restrict__ partB,
                                               float* __restrict__ xx,
                                               float* __restrict__ yy)
{
  int i = blockIdx.x*256 + threadIdx.x;
  const float* part = blockIdx.y ? partB : partA;
  float* out = blockIdx.y ? yy : xx;
  float s = 0.f;
  for (int cs = 0; cs < CS_; ++cs) s += part[(size_t)cs*B_*N_ + i];
  out[i] = s;
}

/* ---- split f32 [B][C][P] -> hi/lo bf16 [B][P][C] + fused sum-of-squares
        partials; z selects src_emb vs tgt_emb ---- */
__global__ __launch_bounds__(256) void ksplit(const float* __restrict__ XA,
                                              const float* __restrict__ XB,
                                              unsigned short* __restrict__ XhA,
                                              unsigned short* __restrict__ XlA,
                                              unsigned short* __restrict__ XhB,
                                              unsigned short* __restrict__ XlB,
                                              float* __restrict__ sqpartA,
                                              float* __restrict__ sqpartB)
{
  __shared__ float tile[64][65];  /* [p][c] */
  int p0 = blockIdx.x*64, c0 = blockIdx.y*64;
  int zb = blockIdx.z;
  int b = zb & (B_-1);
  int side = zb >> 3;
  const float* X = side ? XB : XA;
  unsigned short* Xh = side ? XhB : XhA;
  unsigned short* Xl = side ? XlB : XlA;
  float* sqpart = side ? sqpartB : sqpartA;
  int cs = blockIdx.y;
  int t = threadIdx.x;
  const float* base = X + ((size_t)b*C_ + c0)*N_ + p0;
  int px = (t & 15)*4, cy = t >> 4;
#pragma unroll
  for (int i = 0; i < 4; ++i) {
    int c = cy + i*16;
    float4 v = *(const float4*)(base + (size_t)c*N_ + px);
    tile[px+0][c] = v.x; tile[px+1][c] = v.y; tile[px+2][c] = v.z; tile[px+3][c] = v.w;
  }
  __syncthreads();
  int cx = (t & 15)*4, py = t >> 4;
  unsigned short* oh = Xh + ((size_t)b*N_ + p0)*C_ + c0;
  unsigned short* ol = Xl + ((size_t)b*N_ + p0)*C_ + c0;
#pragma unroll
  for (int i = 0; i < 4; ++i) {
    int p = py + i*16;
    float v0 = tile[p][cx], v1 = tile[p][cx+1], v2 = tile[p][cx+2], v3 = tile[p][cx+3];
    ushort4 h, l;
    h.x = f2bf(v0); l.x = f2bf(v0 - bf2f(h.x));
    h.y = f2bf(v1); l.y = f2bf(v1 - bf2f(h.y));
    h.z = f2bf(v2); l.z = f2bf(v2 - bf2f(h.z));
    h.w = f2bf(v3); l.w = f2bf(v3 - bf2f(h.w));
    *(ushort4*)(oh + (size_t)p*C_ + cx) = h;
    *(ushort4*)(ol + (size_t)p*C_ + cx) = l;
    float sqv = v0*v0 + v1*v1 + v2*v2 + v3*v3;
#pragma unroll
    for (int off = 1; off < 16; off <<= 1) sqv += __shfl_xor(sqv, off, 16);
    if ((t & 15) == 0) sqpart[((size_t)cs*B_ + b)*N_ + p0 + p] = sqv;
  }
}

/* ---- MFMA GEMM: E = exp(2*(Ah+Al)^T(Bh+Bl) - xx - yy), 3-term split-bf16.
        SINGLE-buffered 32KB LDS (4 blocks/CU; TLP hides the stage drain per
        m114) with global_load_lds width-16, pre-swizzled global source
        (slot' = slot ^ ((row>>1)&3)) + same XOR on ds_read (conflict-free).
        XCD-aware tile swizzle. Epilogue fuses row/col stat partials. ---- */
__global__ __launch_bounds__(256, 1) void kgemm_mfma(
    const unsigned short* __restrict__ Ahg, const unsigned short* __restrict__ Alg,
    const unsigned short* __restrict__ Bhg, const unsigned short* __restrict__ Blg,
    const float* __restrict__ xx, const float* __restrict__ yy,
    float* __restrict__ E, float* __restrict__ rowps, float* __restrict__ rowpm,
    float* __restrict__ colps, int b_off)
{
  __shared__ unsigned short smem[4*128*32];   /* 32768 B: 4 ops x 8KB */

  /* XCD swizzle (bijective permutation of the 16x16 tile grid) */
  int sflat = blockIdx.x + 16*blockIdx.y;     /* 0..255 */
  int xcd = sflat & 7, si = sflat >> 3;       /* si in 0..31 */
  int ka = xcd >> 1, kb = xcd & 1;
  int bn = ka*4 + (si & 3);
  int bm = kb*8 + (si >> 2);
  int bz = blockIdx.z;
  int b = b_off + bz;
  int t = threadIdx.x;
  int lane = t & 63, w = t >> 6;
  int wr = (w >> 1)*64, wc = (w & 1)*64;
  int lrow = lane & 15, lgr = (lane >> 4)*8;
  size_t abase = ((size_t)b*N_ + (size_t)bn*128)*C_;
  size_t bbase = ((size_t)b*M_ + (size_t)bm*128)*C_;
  int lr4 = lane >> 2;          /* 0..15: row within 16-row chunk */
  /* pre-swizzled global source column: slot XOR'd by ((row>>1)&3) */
  int lc4s = ((lane & 3)*8) ^ (((lr4 >> 1) & 3) << 3);
  /* fragment-read swizzle: (row>>1)&3 == (lrow>>1)&3 */
  int lgr_sw = lgr ^ (((lrow >> 1) & 3) << 3);

  f32x4 acc[4][4];
#pragma unroll
  for (int i = 0; i < 4; ++i)
#pragma unroll
    for (int j = 0; j < 4; ++j) acc[i][j] = (f32x4){0.f, 0.f, 0.f, 0.f};

#define ISSUE(K0) do { \
    _Pragma("unroll") \
    for (int q = 0; q < 2; ++q) { \
      int rblk = w*2 + q; \
      size_t roff = (size_t)(rblk*16 + lr4)*C_ + (K0) + lc4s; \
      unsigned short* ldsb = smem + rblk*512; \
      __builtin_amdgcn_global_load_lds((const void*)(Ahg + abase + roff), (void*)(ldsb),         16, 0, 0); \
      __builtin_amdgcn_global_load_lds((const void*)(Alg + abase + roff), (void*)(ldsb + 4096),  16, 0, 0); \
      __builtin_amdgcn_global_load_lds((const void*)(Bhg + bbase + roff), (void*)(ldsb + 8192),  16, 0, 0); \
      __builtin_amdgcn_global_load_lds((const void*)(Blg + bbase + roff), (void*)(ldsb + 12288), 16, 0, 0); \
    } \
  } while (0)

  unsigned short* Ahs = smem;
  unsigned short* Als = smem + 4096;
  unsigned short* Bhs = smem + 8192;
  unsigned short* Bls = smem + 12288;
  for (int ks = 0; ks < 16; ++ks) {
    ISSUE(ks*32);
    __syncthreads();                  /* drains gload vmcnt + syncs */
    bf16x8 ah[4], al[4], bh[4], bl[4];
#pragma unroll
    for (int f = 0; f < 4; ++f) {
      int ra = (wr + f*16 + lrow)*32 + lgr_sw;
      int rb = (wc + f*16 + lrow)*32 + lgr_sw;
      ah[f] = *(const bf16x8*)&Ahs[ra];
      al[f] = *(const bf16x8*)&Als[ra];
      bh[f] = *(const bf16x8*)&Bhs[rb];
      bl[f] = *(const bf16x8*)&Bls[rb];
    }
#pragma unroll
    for (int fi = 0; fi < 4; ++fi)
#pragma unroll
      for (int fj = 0; fj < 4; ++fj) {
        acc[fi][fj] = __builtin_amdgcn_mfma_f32_16x16x32_bf16(ah[fi], bh[fj], acc[fi][fj], 0, 0, 0);
        acc[fi][fj] = __builtin_amdgcn_mfma_f32_16x16x32_bf16(ah[fi], bl[fj], acc[fi][fj], 0, 0, 0);
        acc[fi][fj] = __builtin_amdgcn_mfma_f32_16x16x32_bf16(al[fi], bh[fj], acc[fi][fj], 0, 0, 0);
      }
    __syncthreads();                  /* all reads done before next overwrite */
  }
#undef ISSUE

  /* ---- two-pass epilogue (64x128 f32 LDS tile = 32768B exact fit) ---- */
  float* eps = (float*)smem;
  float* Eb = E + (size_t)bz*N_*M_;
  int lg = lane >> 4;                    /* 0..3 */
  int row0 = t >> 5;                     /* 0..7 */
  int c4 = (t & 31)*4;                   /* 0..124 */
  const float* yb = yy + b*M_ + bm*128;
  float4 vy = *(const float4*)(yb + c4);
  float ca0 = 0.f, ca1 = 0.f, ca2 = 0.f, ca3 = 0.f;   /* column partials */
#pragma unroll
  for (int pass = 0; pass < 2; ++pass) {
    __syncthreads();
    if ((w >> 1) == pass) {
#pragma unroll
      for (int fi = 0; fi < 4; ++fi) {
        int nl = lg*4 + fi*16;
#pragma unroll
        for (int fj = 0; fj < 4; ++fj) {
          int ml = wc + (lane & 15) + fj*16;
#pragma unroll
          for (int r = 0; r < 4; ++r)
            eps[(nl + r)*128 + ml] = acc[fi][fj][r];
        }
      }
    }
    __syncthreads();
#pragma unroll
    for (int it = 0; it < 8; ++it) {
      int row = it*8 + row0;
      int gn = bn*128 + pass*64 + row;
      float xv = xx[b*N_ + gn];
      float4 s = *(float4*)&eps[row*128 + c4];
      float4 o;
      o.x = expf(2.f*s.x - xv - vy.x);
      o.y = expf(2.f*s.y - xv - vy.y);
      o.z = expf(2.f*s.z - xv - vy.z);
      o.w = expf(2.f*s.w - xv - vy.w);
      *(float4*)(Eb + (size_t)gn*M_ + bm*128 + c4) = o;
      float rs = o.x + o.y + o.z + o.w;
      float rm2 = fmaxf(fmaxf(o.x, o.y), fmaxf(o.z, o.w));
      ca0 += o.x; ca1 += o.y; ca2 += o.z; ca3 += o.w;
#pragma unroll
      for (int off = 16; off > 0; off >>= 1) {
        rs += __shfl_xor(rs, off, 32);
        rm2 = fmaxf(rm2, __shfl_xor(rm2, off, 32));
      }
      if ((t & 31) == 0) {
        rowps[(size_t)bm*B_*N_ + (size_t)b*N_ + gn] = rs;
        rowpm[(size_t)bm*B_*N_ + (size_t)b*N_ + gn] = rm2;
      }
    }
  }
  __syncthreads();
  float* colsh = (float*)smem;           /* [8][128] */
  colsh[row0*128 + c4+0] = ca0;
  colsh[row0*128 + c4+1] = ca1;
  colsh[row0*128 + c4+2] = ca2;
  colsh[row0*128 + c4+3] = ca3;
  __syncthreads();
  if (t < 128) {
    float s = 0.f;
#pragma unroll
    for (int g = 0; g < 8; ++g) s += colsh[g*128 + t];
    colps[(size_t)bn*B_*M_ + (size_t)b*M_ + bm*128 + t] = s;
  }
}

/* ---- fused: y==0 -> rowZ/rowSmax from row partials; y==1 -> colZ0 ---- */
__global__ __launch_bounds__(256) void kstatcomb(
    const float* __restrict__ rowps, const float* __restrict__ rowpm,
    const float* __restrict__ colps,
    float* __restrict__ rowZf, float* __restrict__ rowSmax,
    float* __restrict__ colZ0f, int b_off)
{
  int i = blockIdx.x*256 + threadIdx.x;
  size_t gi = (size_t)b_off*N_ + i;
  if (blockIdx.y == 0) {
    double s = 0.0; float mx = 0.f;
#pragma unroll
    for (int k = 0; k < 16; ++k) {
      s += (double)rowps[(size_t)k*B_*N_ + gi];
      mx = fmaxf(mx, rowpm[(size_t)k*B_*N_ + gi]);
    }
    float zf = (float)s;
    rowZf[gi] = zf;
    rowSmax[gi] = mx * (1.f / zf);  /* same RN(1/zf) recomputed in kwcorr */
  } else {
    double s = 0.0;
#pragma unroll
    for (int k = 0; k < 16; ++k) s += (double)colps[(size_t)k*B_*M_ + gi];
    colZ0f[gi] = (float)s;
  }
}

/* ---- fused cross pass: one E read -> colSp (sum_n E/rowZ) AND rowSp
        (sum_m E/colZ0), f64 partials; reciprocals precomputed in LDS. ---- */
__global__ __launch_bounds__(256) void kcross(const float* __restrict__ E,
                                              const float* __restrict__ rowZf,
                                              const float* __restrict__ colZ0f,
                                              double* __restrict__ colSp,
                                              double* __restrict__ rowSp, int b_off)
{
  __shared__ float tile[64*129];   /* 33024 B */
  __shared__ double rzinv[64];
  __shared__ double czinv[128];
  __shared__ double shd[256];
  int rc = blockIdx.x, cc = blockIdx.y, bz = blockIdx.z;
  int b = b_off + bz;
  int r0 = rc*64, c0 = cc*128;
  int t = threadIdx.x;
  const float* Eb = E + (size_t)bz*N_*M_;
  {
    int rr = t >> 5, cq = (t & 31)*4;
#pragma unroll
    for (int it = 0; it < 8; ++it) {
      int row = it*8 + rr;
      float4 v = *(const float4*)(Eb + (size_t)(r0+row)*M_ + c0 + cq);
      tile[row*129 + cq+0] = v.x;
      tile[row*129 + cq+1] = v.y;
      tile[row*129 + cq+2] = v.z;
      tile[row*129 + cq+3] = v.w;
    }
  }
  if (t < 64) rzinv[t] = 1.0 / (double)rowZf[(size_t)b*N_ + r0 + t];
  if (t >= 128) czinv[t-128] = 1.0 / (double)colZ0f[(size_t)b*M_ + c0 + (t-128)];
  __syncthreads();
  {
    int j = t & 127, rg = t >> 7;
    double a = 0.0;
    for (int rr = rg*32; rr < rg*32 + 32; ++rr)
      a += (double)tile[rr*129 + j] * rzinv[rr];
    shd[rg*128 + j] = a;
  }
  __syncthreads();
  if (t < 128)
    colSp[(size_t)rc*B_*M_ + (size_t)b*M_ + c0 + t] = shd[t] + shd[128 + t];
  __syncthreads();
  {
    int r = t & 63, h = t >> 6;
    double a = 0.0;
    for (int j = h*32; j < h*32 + 32; ++j)
      a += (double)tile[r*129 + j] * czinv[j];
    shd[h*64 + r] = a;
  }
  __syncthreads();
  if (t < 64)
    rowSp[(size_t)cc*B_*N_ + (size_t)b*N_ + r0 + t] = shd[t] + shd[64+t] + shd[128+t] + shd[192+t];
}

/* ---- fused: y==0 -> col_sum (32 partials); y==1 -> row_sum (16 partials) ---- */
__global__ __launch_bounds__(256) void kcombab(const double* __restrict__ colSp,
                                               const double* __restrict__ rowSp,
                                               double* __restrict__ col_sum,
                                               double* __restrict__ row_sum, int b_off)
{
  int i = blockIdx.x*256 + threadIdx.x;
  if (blockIdx.y == 0) {
    size_t gi = (size_t)b_off*M_ + i;
    double s = 0.0;
    for (int k = 0; k < 32; ++k) s += colSp[(size_t)k*B_*M_ + gi];
    col_sum[gi] = s;
  } else {
    size_t gi = (size_t)b_off*N_ + i;
    double s = 0.0;
    for (int k = 0; k < 16; ++k) s += rowSp[(size_t)k*B_*N_ + gi];
    row_sum[gi] = s;
  }
}

/* ---- exact K-th smallest via rank count; z selects col/row side ---- */
__global__ __launch_bounds__(256) void kkth(const double* __restrict__ col_sum,
                                            const double* __restrict__ row_sum,
                                            double* __restrict__ kth_c,
                                            double* __restrict__ kth_r, int b_off)
{
  __shared__ double sv[2048];
  int b = b_off + blockIdx.y;
  const double* v = (blockIdx.z == 0 ? col_sum : row_sum) + b*2048;
  double* kth = (blockIdx.z == 0 ? kth_c : kth_r);
  int t = threadIdx.x;
  for (int i = t; i < 2048; i += 256) sv[i] = v[i];
  __syncthreads();
  int i = blockIdx.x*256 + t;
  double vi = sv[i];
  int lt = 0, le = 0;
  for (int j = 0; j < 2048; ++j) { double vj = sv[j]; lt += (vj < vi); le += (vj <= vi); }
  if (lt < KSEL && KSEL <= le) kth[b] = vi;
}

/* ---- masks; y selects col/row side ---- */
__global__ __launch_bounds__(256) void kmask(const double* __restrict__ col_sum,
                                             const double* __restrict__ row_sum,
                                             const double* __restrict__ kth_c,
                                             const double* __restrict__ kth_r,
                                             unsigned char* __restrict__ colmask,
                                             unsigned char* __restrict__ rowmask,
                                             float* __restrict__ out, int b_off)
{
  int side = blockIdx.y;
  const double* vals = side ? row_sum : col_sum;
  const double* kth = side ? kth_r : kth_c;
  unsigned char* m8 = side ? rowmask : colmask;
  float* mout = out + (side ? O_MSRC : O_MTGT);
  int i = blockIdx.x*256 + threadIdx.x;
  int b = b_off + i/2048, j = i & 2047;
  bool m = vals[b*2048 + j] < kth[b];
  m8[b*2048 + j] = m ? 1 : 0;
  mout[b*2048 + j] = m ? 1.f : 0.f;
}

/* ---- sparse renorm + vsi + src_corr: float4 register-cached row,
        wave-shuffle reductions, reciprocal multiplies ---- */
__global__ __launch_bounds__(256) void kwcorr(
    const float* __restrict__ E, const float* __restrict__ rowZf,
    const float* __restrict__ rowSmax,
    const unsigned char* __restrict__ rowmask, const unsigned char* __restrict__ colmask,
    const float* __restrict__ tgt, float* __restrict__ vsi,
    float* __restrict__ corrf, float* __restrict__ corr_out, int b_off)
{
  __shared__ float shred[20];
  int r = blockIdx.x, t = threadIdx.x;
  int bz = r / N_, n = r % N_;
  int b = b_off + bz;
  const float* row = E + (size_t)bz*N_*M_ + (size_t)n*M_;
  float rinv = 1.f / rowZf[b*N_+n];       /* bit-identical to kstatcomb's rinv */
  int lane = t & 63, w = t >> 6;
  float rmax = rowSmax[b*N_+n];
  int rm = rowmask[b*N_+n];
  const unsigned char* cm = colmask + b*M_;
  float v0_, v1_, v2_, v3_, v4_, v5_, v6_, v7_;
  unsigned kp = 0;
  float s = 0.f;
  {
    int m0 = t*4;
    float4 e0 = *(const float4*)(row + m0);
    float4 e1 = *(const float4*)(row + m0 + 1024);
    v0_ = e0.x*rinv; v1_ = e0.y*rinv; v2_ = e0.z*rinv; v3_ = e0.w*rinv;
    v4_ = e1.x*rinv; v5_ = e1.y*rinv; v6_ = e1.z*rinv; v7_ = e1.w*rinv;
    uchar4 c0v = *(const uchar4*)(cm + m0);
    uchar4 c1v = *(const uchar4*)(cm + m0 + 1024);
    bool k0 = rm || c0v.x || (v0_ >= rmax); if (k0) { s += v0_; kp |= 1u; }
    bool k1 = rm || c0v.y || (v1_ >= rmax); if (k1) { s += v1_; kp |= 2u; }
    bool k2 = rm || c0v.z || (v2_ >= rmax); if (k2) { s += v2_; kp |= 4u; }
    bool k3 = rm || c0v.w || (v3_ >= rmax); if (k3) { s += v3_; kp |= 8u; }
    bool k4 = rm || c1v.x || (v4_ >= rmax); if (k4) { s += v4_; kp |= 16u; }
    bool k5 = rm || c1v.y || (v5_ >= rmax); if (k5) { s += v5_; kp |= 32u; }
    bool k6 = rm || c1v.z || (v6_ >= rmax); if (k6) { s += v6_; kp |= 64u; }
    bool k7 = rm || c1v.w || (v7_ >= rmax); if (k7) { s += v7_; kp |= 128u; }
  }
#pragma unroll
  for (int off = 32; off; off >>= 1) s += __shfl_xor(s, off, 64);
  if (!lane) shred[w] = s;
  __syncthreads();
  s = shred[0] + shred[1] + shred[2] + shred[3];
  float d = (s < EPS_) ? EPS_ : s;
  float dinv = 1.f / d;
  const float* t0 = tgt + (size_t)b*3*M_;
  float vs = 0.f, a0 = 0.f, a1 = 0.f, a2 = 0.f;
  {
    int m0 = t*4;
    float4 tx0 = *(const float4*)(t0 + m0);
    float4 ty0 = *(const float4*)(t0 + M_ + m0);
    float4 tz0 = *(const float4*)(t0 + 2*M_ + m0);
    float w0 = (kp & 1u)   ? v0_*dinv : 0.f;
    float w1 = (kp & 2u)   ? v1_*dinv : 0.f;
    float w2 = (kp & 4u)   ? v2_*dinv : 0.f;
    float w3 = (kp & 8u)   ? v3_*dinv : 0.f;
    vs += w0+w1+w2+w3;
    a0 += w0*tx0.x + w1*tx0.y + w2*tx0.z + w3*tx0.w;
    a1 += w0*ty0.x + w1*ty0.y + w2*ty0.z + w3*ty0.w;
    a2 += w0*tz0.x + w1*tz0.y + w2*tz0.z + w3*tz0.w;
    float4 tx1 = *(const float4*)(t0 + m0 + 1024);
    float4 ty1 = *(const float4*)(t0 + M_ + m0 + 1024);
    float4 tz1 = *(const float4*)(t0 + 2*M_ + m0 + 1024);
    float w4 = (kp & 16u)  ? v4_*dinv : 0.f;
    float w5 = (kp & 32u)  ? v5_*dinv : 0.f;
    float w6 = (kp & 64u)  ? v6_*dinv : 0.f;
    float w7 = (kp & 128u) ? v7_*dinv : 0.f;
    vs += w4+w5+w6+w7;
    a0 += w4*tx1.x + w5*tx1.y + w6*tx1.z + w7*tx1.w;
    a1 += w4*ty1.x + w5*ty1.y + w6*ty1.z + w7*ty1.w;
    a2 += w4*tz1.x + w5*tz1.y + w6*tz1.z + w7*tz1.w;
  }
#pragma unroll
  for (int off = 32; off; off >>= 1) {
    vs += __shfl_xor(vs, off, 64);
    a0 += __shfl_xor(a0, off, 64);
    a1 += __shfl_xor(a1, off, 64);
    a2 += __shfl_xor(a2, off, 64);
  }
  if (!lane) {
    shred[4 + w] = vs; shred[8 + w] = a0; shred[12 + w] = a1; shred[16 + w] = a2;
  }
  __syncthreads();
  if (!t) {
    float vsT = shred[4]+shred[5]+shred[6]+shred[7];
    float a0T = shred[8]+shred[9]+shred[10]+shred[11];
    float a1T = shred[12]+shred[13]+shred[14]+shred[15];
    float a2T = shred[16]+shred[17]+shred[18]+shred[19];
    vsi[b*N_+n] = rm ? 0.f : vsT;
    size_t o = (size_t)b*3*N_ + n;
    corrf[o] = a0T; corrf[o+N_] = a1T; corrf[o+2*N_] = a2T;
    corr_out[o]      = a0T;
    corr_out[o+N_]   = a1T;
    corr_out[o+2*N_] = a2T;
  }
}

__global__ __launch_bounds__(256) void ksumvsi(const float* __restrict__ vsi,
                                               float* __restrict__ out)
{
  __shared__ double shd[256];
  int b = blockIdx.x;
  double s = 0.0;
  for (int n = threadIdx.x; n < N_; n += 256) s += (double)vsi[b*N_+n];
  s = blk_sumd(s, shd);
  if (!threadIdx.x) out[b] = (float)s;
}

__global__ __launch_bounds__(256) void kweights(const float* __restrict__ vsi,
                                                const float* __restrict__ sumvsi,
                                                float* __restrict__ srcw,
                                                float* __restrict__ wout)
{
  int i = blockIdx.x*256 + threadIdx.x;
  if (i >= B_*N_) return;
  int b = i / N_;
  float w = vsi[i] / sumvsi[b];
  srcw[i] = w;
  wout[i] = w;
}

__global__ __launch_bounds__(256) void kcov(const float* __restrict__ srcw,
                                            const float* __restrict__ src,
                                            const float* __restrict__ corrf,
                                            double* covd, double* cad, double* cbd)
{
  __shared__ double sh[256];
  int b = blockIdx.x, t = threadIdx.x;
  const float* w = srcw + b*N_;
  const float* a = src  + (size_t)b*3*N_;
  const float* bb = corrf + (size_t)b*3*N_;
  double sw = 0.0;
  for (int n = t; n < N_; n += 256) sw += (double)w[n];
  sw = blk_sumd(sw, sh);
  double inv = 1.0/(sw + 1e-5);
  double p0=0,p1=0,p2=0,p3=0,p4=0,p5=0;
  for (int n = t; n < N_; n += 256) {
    double wn = (double)w[n]*inv;
    p0 += (double)a[n]*wn;      p1 += (double)a[N_+n]*wn;   p2 += (double)a[2*N_+n]*wn;
    p3 += (double)bb[n]*wn;     p4 += (double)bb[N_+n]*wn;  p5 += (double)bb[2*N_+n]*wn;
  }
  double ca0 = blk_sumd(p0, sh), ca1 = blk_sumd(p1, sh), ca2 = blk_sumd(p2, sh);
  double cb0 = blk_sumd(p3, sh), cb1 = blk_sumd(p4, sh), cb2 = blk_sumd(p5, sh);
  double c[9] = {0,0,0,0,0,0,0,0,0};
  for (int n = t; n < N_; n += 256) {
    double wn = (double)w[n]*inv;
    double a0 = (double)a[n]-ca0, a1d = (double)a[N_+n]-ca1, a2d = (double)a[2*N_+n]-ca2;
    double b0 = ((double)bb[n]-cb0)*wn, b1 = ((double)bb[N_+n]-cb1)*wn, b2 = ((double)bb[2*N_+n]-cb2)*wn;
    c[0]+=a0*b0; c[1]+=a0*b1; c[2]+=a0*b2;
    c[3]+=a1d*b0; c[4]+=a1d*b1; c[5]+=a1d*b2;
    c[6]+=a2d*b0; c[7]+=a2d*b1; c[8]+=a2d*b2;
  }
  for (int k = 0; k < 9; ++k) {
    double rr = blk_sumd(c[k], sh);
    if (!t) covd[b*9+k] = rr;
  }
  if (!t) {
    cad[b*3+0]=ca0; cad[b*3+1]=ca1; cad[b*3+2]=ca2;
    cbd[b*3+0]=cb0; cbd[b*3+1]=cb1; cbd[b*3+2]=cb2;
  }
}

/* ---- 3x3 Kabsch via Jacobi eigendecomposition of H^T H (f64) ---- */
__global__ void ksvd(const double* __restrict__ covd, const double* __restrict__ cad,
                     const double* __restrict__ cbd, float* out)
{
  int b = threadIdx.x;
  if (b >= B_) return;
  double H[3][3];
  for (int i = 0; i < 3; ++i) for (int j = 0; j < 3; ++j) H[i][j] = covd[b*9+i*3+j];
  double A[3][3];
  for (int i = 0; i < 3; ++i)
    for (int j = 0; j < 3; ++j) {
      double s = 0.0;
      for (int l = 0; l < 3; ++l) s += H[l][i]*H[l][j];
      A[i][j] = s;
    }
  double V[3][3] = {{1,0,0},{0,1,0},{0,0,1}};
  const int PP[3] = {0,0,1}, QQ[3] = {1,2,2};
  for (int sweep = 0; sweep < 24; ++sweep) {
    double off = fabs(A[0][1])+fabs(A[0][2])+fabs(A[1][2]);
    if (off < 1e-28) break;
    for (int r = 0; r < 3; ++r) {
      int p = PP[r], q = QQ[r];
      double apq = A[p][q];
      if (fabs(apq) < 1e-300) continue;
      double th = (A[q][q]-A[p][p])/(2.0*apq);
      double tt = (th >= 0.0 ? 1.0 : -1.0)/(fabs(th)+sqrt(th*th+1.0));
      double cc = 1.0/sqrt(tt*tt+1.0), ss = tt*cc;
      for (int k = 0; k < 3; ++k) {
        double akp = A[k][p], akq = A[k][q];
        A[k][p] = cc*akp - ss*akq; A[k][q] = ss*akp + cc*akq;
      }
      for (int k = 0; k < 3; ++k) {
        double apk = A[p][k], aqk = A[q][k];
        A[p][k] = cc*apk - ss*aqk; A[q][k] = ss*apk + cc*aqk;
      }
      for (int k = 0; k < 3; ++k) {
        double vkp = V[k][p], vkq = V[k][q];
        V[k][p] = cc*vkp - ss*vkq; V[k][q] = ss*vkp + cc*vkq;
      }
    }
  }
  double lam[3] = {A[0][0], A[1][1], A[2][2]};
  int idx[3] = {0,1,2};
  for (int i = 0; i < 2; ++i)
    for (int j = i+1; j < 3; ++j)
      if (lam[idx[j]] > lam[idx[i]]) { int tmp = idx[i]; idx[i] = idx[j]; idx[j] = tmp; }
  double Vs[3][3], sig[3];
  for (int i = 0; i < 3; ++i) {
    for (int k = 0; k < 3; ++k) Vs[k][i] = V[k][idx[i]];
    double l = lam[idx[i]];
    sig[i] = sqrt(l > 0.0 ? l : 0.0);
  }
  double U[3][3];
  for (int i = 0; i < 3; ++i) {
    double inv = sig[i] > 1e-300 ? 1.0/sig[i] : 0.0;
    for (int k = 0; k < 3; ++k) {
      double u = H[k][0]*Vs[0][i] + H[k][1]*Vs[1][i] + H[k][2]*Vs[2][i];
      U[k][i] = u*inv;
    }
  }
  if (sig[2] <= 1e-9*sig[0]) {
    U[0][2] = U[1][0]*U[2][1] - U[2][0]*U[1][1];
    U[1][2] = U[2][0]*U[0][1] - U[0][0]*U[2][1];
    U[2][2] = U[0][0]*U[1][1] - U[1][0]*U[0][1];
  }
  double detH = H[0][0]*(H[1][1]*H[2][2]-H[1][2]*H[2][1])
              - H[0][1]*(H[1][0]*H[2][2]-H[1][2]*H[2][0])
              + H[0][2]*(H[1][0]*H[2][1]-H[1][1]*H[2][0]);
  double s3[3] = {1.0, 1.0, detH > 0.0 ? 1.0 : -1.0};
  double R[3][3];
  for (int d = 0; d < 3; ++d)
    for (int e = 0; e < 3; ++e) {
      double s = 0.0;
      for (int i = 0; i < 3; ++i) s += s3[i]*Vs[d][i]*U[e][i];
      R[d][e] = s;
    }
  double tr[3];
  for (int d = 0; d < 3; ++d)
    tr[d] = cbd[b*3+d] - (R[d][0]*cad[b*3+0] + R[d][1]*cad[b*3+1] + R[d][2]*cad[b*3+2]);
  for (int d = 0; d < 3; ++d)
    for (int e = 0; e < 3; ++e)
      out[O_ROT + b*9 + d*3 + e] = (float)R[d][e];
  for (int d = 0; d < 3; ++d)
    out[O_TR + b*3 + d] = (float)tr[d];
}

__global__ void kfail(float* out, float v) { out[0] = v; }

extern "C" void kernel_launch(void* const* d_in, const int* in_sizes, int n_in,
                              void* d_out, int out_size, void* d_ws, size_t ws_size,
                              hipStream_t stream) {
  float* out = (float*)d_out;
  (void)out_size;

  /* input-order auto-detect: dict (src,tgt,src_emb,tgt_emb) vs alphabetical */
  int i_tgt = 1, i_semb = 2;
  if (n_in == 4 && in_sizes[1] == B_*C_*N_) { i_semb = 1; i_tgt = 2; }
  const float* src  = (const float*)d_in[0];
  const float* tgt  = (const float*)d_in[i_tgt];
  const float* semb = (const float*)d_in[i_semb];
  const float* temb = (const float*)d_in[3];

  char* w = (char*)d_ws;
  auto alloc = [&](size_t bytes) { char* p = w; w += (bytes + 255)/256*256; return p; };
  float*  sqpartA = (float*)alloc((size_t)CS_*B_*N_*4);
  float*  sqpartB = (float*)alloc((size_t)CS_*B_*N_*4);
  float*  xx      = (float*)alloc((size_t)B_*N_*4);
  float*  yy      = (float*)alloc((size_t)B_*M_*4);
  float*  rowZf   = (float*)alloc((size_t)B_*N_*4);
  float*  rowSmax = (float*)alloc((size_t)B_*N_*4);
  float*  colZ0f  = (float*)alloc((size_t)B_*M_*4);
  float*  rowps   = (float*)alloc((size_t)16*B_*N_*4);   /* partial-major [bm][b][n] */
  float*  rowpm   = (float*)alloc((size_t)16*B_*N_*4);
  float*  colps   = (float*)alloc((size_t)16*B_*M_*4);   /* [bn][b][m] */
  double* colSp   = (double*)alloc((size_t)32*B_*M_*8);  /* [rc][b][m] */
  double* rowSp   = (double*)alloc((size_t)16*B_*N_*8);  /* [cc][b][n] */
  double* col_sum = (double*)alloc((size_t)B_*M_*8);
  double* row_sum = (double*)alloc((size_t)B_*N_*8);
  double* kth_c   = (double*)alloc((size_t)B_*8);
  double* kth_r   = (double*)alloc((size_t)B_*8);
  unsigned char* rowmask = (unsigned char*)alloc((size_t)B_*N_);
  unsigned char* colmask = (unsigned char*)alloc((size_t)B_*M_);
  float*  vsi     = (float*)alloc((size_t)B_*N_*4);
  float*  srcw    = (float*)alloc((size_t)B_*N_*4);
  float*  sumvsi  = (float*)alloc((size_t)B_*4);
  float*  corrf   = (float*)alloc((size_t)B_*3*N_*4);
  double* covd = (double*)alloc((size_t)B_*9*8);
  double* cad  = (double*)alloc((size_t)B_*3*8);
  double* cbd  = (double*)alloc((size_t)B_*3*8);
  /* split-bf16 operand arrays [B][pos][C] */
  unsigned short* Ahg = (unsigned short*)alloc((size_t)B_*N_*C_*2);
  unsigned short* Alg = (unsigned short*)alloc((size_t)B_*N_*C_*2);
  unsigned short* Bhg = (unsigned short*)alloc((size_t)B_*M_*C_*2);
  unsigned short* Blg = (unsigned short*)alloc((size_t)B_*M_*C_*2);

  size_t used = (size_t)(w - (char*)d_ws);
  size_t rem = ws_size > used ? ws_size - used : 0;
  size_t oneE = (size_t)N_*M_*sizeof(float);
  int bc = (int)(rem / oneE);
  if (bc < 1) { kfail<<<1, 1, 0, stream>>>(out, 32768.f); return; }
  if (bc > B_) bc = B_;
  float* E = (float*)w;

  /* split + transpose both embeddings (fused sum-of-squares partials) */
  ksplit<<<dim3(N_/64, C_/64, 2*B_), 256, 0, stream>>>(semb, temb, Ahg, Alg, Bhg, Blg,
                                                       sqpartA, sqpartB);
  ksqcomb<<<dim3((B_*N_)/256, 2), 256, 0, stream>>>(sqpartA, sqpartB, xx, yy);

  for (int b0 = 0; b0 < B_; b0 += bc) {
    int cur = (B_ - b0 < bc) ? (B_ - b0) : bc;
    kgemm_mfma<<<dim3(N_/128, M_/128, cur), 256, 0, stream>>>(Ahg, Alg, Bhg, Blg,
                                                              xx, yy, E, rowps, rowpm, colps, b0);
    kstatcomb<<<dim3(cur*N_/256, 2), 256, 0, stream>>>(rowps, rowpm, colps,
                                                       rowZf, rowSmax, colZ0f, b0);
    kcross   <<<dim3(N_/64, M_/128, cur), 256, 0, stream>>>(E, rowZf, colZ0f, colSp, rowSp, b0);
    kcombab  <<<dim3(cur*M_/256, 2), 256, 0, stream>>>(colSp, rowSp, col_sum, row_sum, b0);
    kkth     <<<dim3(8, cur, 2), 256, 0, stream>>>(col_sum, row_sum, kth_c, kth_r, b0);
    kmask    <<<dim3(cur*8, 2), 256, 0, stream>>>(col_sum, row_sum, kth_c, kth_r,
                                                  colmask, rowmask, out, b0);
    kwcorr   <<<cur*N_, 256, 0, stream>>>(E, rowZf, rowSmax, rowmask, colmask, tgt,
                                          vsi, corrf, out + O_CORR, b0);
  }

  ksumvsi <<<B_, 256, 0, stream>>>(vsi, sumvsi);
  kweights<<<(B_*N_+255)/256, 256, 0, stream>>>(vsi, sumvsi, srcw, out + O_W);
  kcov    <<<B_, 256, 0, stream>>>(srcw, src, corrf, covd, cad, cbd);
  ksvd    <<<1, 64, 0, stream>>>(covd, cad, cbd, out);
}

// Round 19
// 286.150 us; speedup vs baseline: 1.9427x; 1.0193x over previous
//
#include <hip/hip_runtime.h>
#include <math.h>

#define B_ 8
#define C_ 512
#define N_ 2048
#define M_ 2048
#define KSEL 614          /* int(2048*0.3) */
#define EPS_ 1e-5f
#define CS_ 8             /* c-chunks (C/64) for sq partials */

#define O_CORR 0
#define O_W    (B_*3*N_)          /* 49152 */
#define O_MSRC (O_W + B_*N_)      /* 65536 */
#define O_MTGT (O_MSRC + B_*N_)   /* 81920 */
#define O_ROT  (O_MTGT + B_*M_)   /* 98304 */
#define O_TR   (O_ROT + B_*9)     /* 98376 */

typedef short bf16x8 __attribute__((ext_vector_type(8)));
typedef float f32x4 __attribute__((ext_vector_type(4)));

__device__ inline unsigned short f2bf(float f){
  unsigned u = __float_as_uint(f);
  return (unsigned short)((u + 0x7FFFu + ((u >> 16) & 1u)) >> 16);
}
__device__ inline float bf2f(unsigned short h){
  return __uint_as_float(((unsigned)h) << 16);
}

__device__ inline double blk_sumd(double v, double* sh){
  int t = threadIdx.x;
  sh[t] = v; __syncthreads();
  for (int s = 128; s > 0; s >>= 1) { if (t < s) sh[t] += sh[t+s]; __syncthreads(); }
  double r = sh[0]; __syncthreads(); return r;
}

/* ---- combine sq partials -> xx/yy (y selects A/B side) ---- */
__global__ __launch_bounds__(256) void ksqcomb(const float* __restrict__ partA,
                                               const float* __restrict__ partB,
                                               float* __restrict__ xx,
                                               float* __restrict__ yy)
{
  int i = blockIdx.x*256 + threadIdx.x;
  const float* part = blockIdx.y ? partB : partA;
  float* out = blockIdx.y ? yy : xx;
  float s = 0.f;
  for (int cs = 0; cs < CS_; ++cs) s += part[(size_t)cs*B_*N_ + i];
  out[i] = s;
}

/* ---- split f32 [B][C][P] -> hi/lo bf16 [B][P][C] + fused sum-of-squares
        partials; z selects src_emb vs tgt_emb ---- */
__global__ __launch_bounds__(256) void ksplit(const float* __restrict__ XA,
                                              const float* __restrict__ XB,
                                              unsigned short* __restrict__ XhA,
                                              unsigned short* __restrict__ XlA,
                                              unsigned short* __restrict__ XhB,
                                              unsigned short* __restrict__ XlB,
                                              float* __restrict__ sqpartA,
                                              float* __restrict__ sqpartB)
{
  __shared__ float tile[64][65];  /* [p][c] */
  int p0 = blockIdx.x*64, c0 = blockIdx.y*64;
  int zb = blockIdx.z;
  int b = zb & (B_-1);
  int side = zb >> 3;
  const float* X = side ? XB : XA;
  unsigned short* Xh = side ? XhB : XhA;
  unsigned short* Xl = side ? XlB : XlA;
  float* sqpart = side ? sqpartB : sqpartA;
  int cs = blockIdx.y;
  int t = threadIdx.x;
  const float* base = X + ((size_t)b*C_ + c0)*N_ + p0;
  int px = (t & 15)*4, cy = t >> 4;
#pragma unroll
  for (int i = 0; i < 4; ++i) {
    int c = cy + i*16;
    float4 v = *(const float4*)(base + (size_t)c*N_ + px);
    tile[px+0][c] = v.x; tile[px+1][c] = v.y; tile[px+2][c] = v.z; tile[px+3][c] = v.w;
  }
  __syncthreads();
  int cx = (t & 15)*4, py = t >> 4;
  unsigned short* oh = Xh + ((size_t)b*N_ + p0)*C_ + c0;
  unsigned short* ol = Xl + ((size_t)b*N_ + p0)*C_ + c0;
#pragma unroll
  for (int i = 0; i < 4; ++i) {
    int p = py + i*16;
    float v0 = tile[p][cx], v1 = tile[p][cx+1], v2 = tile[p][cx+2], v3 = tile[p][cx+3];
    ushort4 h, l;
    h.x = f2bf(v0); l.x = f2bf(v0 - bf2f(h.x));
    h.y = f2bf(v1); l.y = f2bf(v1 - bf2f(h.y));
    h.z = f2bf(v2); l.z = f2bf(v2 - bf2f(h.z));
    h.w = f2bf(v3); l.w = f2bf(v3 - bf2f(h.w));
    *(ushort4*)(oh + (size_t)p*C_ + cx) = h;
    *(ushort4*)(ol + (size_t)p*C_ + cx) = l;
    float sqv = v0*v0 + v1*v1 + v2*v2 + v3*v3;
#pragma unroll
    for (int off = 1; off < 16; off <<= 1) sqv += __shfl_xor(sqv, off, 16);
    if ((t & 15) == 0) sqpart[((size_t)cs*B_ + b)*N_ + p0 + p] = sqv;
  }
}

/* ---- MFMA GEMM: E = exp(2*(Ah+Al)^T(Bh+Bl) - xx - yy), 3-term split-bf16.
        Double-buffered (2x32KB) global_load_lds width-16, one barrier per
        K-step; pre-swizzled global source (slot' = slot ^ ((row>>1)&3)) +
        same XOR on ds_read -> conflict-free. Linear [128][32] ushort tiles.
        XCD-aware tile swizzle. Epilogue fuses row/col stat partials. ---- */
__global__ __launch_bounds__(256, 1) void kgemm_mfma(
    const unsigned short* __restrict__ Ahg, const unsigned short* __restrict__ Alg,
    const unsigned short* __restrict__ Bhg, const unsigned short* __restrict__ Blg,
    const float* __restrict__ xx, const float* __restrict__ yy,
    float* __restrict__ E, float* __restrict__ rowps, float* __restrict__ rowpm,
    float* __restrict__ colps, int b_off)
{
  __shared__ unsigned short smem[2*4*128*32];   /* 65536 B: 2 bufs x 4 ops x 8KB */

  /* XCD swizzle (bijective permutation of the 16x16 tile grid) */
  int sflat = blockIdx.x + 16*blockIdx.y;     /* 0..255 */
  int xcd = sflat & 7, si = sflat >> 3;       /* si in 0..31 */
  int ka = xcd >> 1, kb = xcd & 1;
  int bn = ka*4 + (si & 3);
  int bm = kb*8 + (si >> 2);
  int bz = blockIdx.z;
  int b = b_off + bz;
  int t = threadIdx.x;
  int lane = t & 63, w = t >> 6;
  int wr = (w >> 1)*64, wc = (w & 1)*64;
  int lrow = lane & 15, lgr = (lane >> 4)*8;
  size_t abase = ((size_t)b*N_ + (size_t)bn*128)*C_;
  size_t bbase = ((size_t)b*M_ + (size_t)bm*128)*C_;
  int lr4 = lane >> 2;          /* 0..15: row within 16-row chunk */
  /* pre-swizzled global source column: slot XOR'd by ((row>>1)&3) */
  int lc4s = ((lane & 3)*8) ^ (((lr4 >> 1) & 3) << 3);
  /* fragment-read swizzle: (row>>1)&3 == (lrow>>1)&3 */
  int lgr_sw = lgr ^ (((lrow >> 1) & 3) << 3);

  f32x4 acc[4][4];
#pragma unroll
  for (int i = 0; i < 4; ++i)
#pragma unroll
    for (int j = 0; j < 4; ++j) acc[i][j] = (f32x4){0.f, 0.f, 0.f, 0.f};

#define ISSUE(bufk, K0) do { \
    unsigned short* bb0 = smem + (bufk)*16384; \
    _Pragma("unroll") \
    for (int q = 0; q < 2; ++q) { \
      int rblk = w*2 + q; \
      size_t roff = (size_t)(rblk*16 + lr4)*C_ + (K0) + lc4s; \
      unsigned short* ldsb = bb0 + rblk*512; \
      __builtin_amdgcn_global_load_lds((const void*)(Ahg + abase + roff), (void*)(ldsb),         16, 0, 0); \
      __builtin_amdgcn_global_load_lds((const void*)(Alg + abase + roff), (void*)(ldsb + 4096),  16, 0, 0); \
      __builtin_amdgcn_global_load_lds((const void*)(Bhg + bbase + roff), (void*)(ldsb + 8192),  16, 0, 0); \
      __builtin_amdgcn_global_load_lds((const void*)(Blg + bbase + roff), (void*)(ldsb + 12288), 16, 0, 0); \
    } \
  } while (0)

  ISSUE(0, 0);
  int cur = 0;
  for (int ks = 0; ks < 16; ++ks) {
    __syncthreads();                  /* drains this wave's gload vmcnt + syncs */
    if (ks < 15) { int k0n = (ks+1)*32; ISSUE(cur^1, k0n); }
    unsigned short* bb = smem + cur*16384;
    unsigned short* Ahs = bb;
    unsigned short* Als = bb + 4096;
    unsigned short* Bhs = bb + 8192;
    unsigned short* Bls = bb + 12288;
    bf16x8 ah[4], al[4], bh[4], bl[4];
#pragma unroll
    for (int f = 0; f < 4; ++f) {
      int ra = (wr + f*16 + lrow)*32 + lgr_sw;
      int rb = (wc + f*16 + lrow)*32 + lgr_sw;
      ah[f] = *(const bf16x8*)&Ahs[ra];
      al[f] = *(const bf16x8*)&Als[ra];
      bh[f] = *(const bf16x8*)&Bhs[rb];
      bl[f] = *(const bf16x8*)&Bls[rb];
    }
#pragma unroll
    for (int fi = 0; fi < 4; ++fi)
#pragma unroll
      for (int fj = 0; fj < 4; ++fj) {
        acc[fi][fj] = __builtin_amdgcn_mfma_f32_16x16x32_bf16(ah[fi], bh[fj], acc[fi][fj], 0, 0, 0);
        acc[fi][fj] = __builtin_amdgcn_mfma_f32_16x16x32_bf16(ah[fi], bl[fj], acc[fi][fj], 0, 0, 0);
        acc[fi][fj] = __builtin_amdgcn_mfma_f32_16x16x32_bf16(al[fi], bh[fj], acc[fi][fj], 0, 0, 0);
      }
    cur ^= 1;
  }
#undef ISSUE

  /* ---- two-pass epilogue (64x132 f32 LDS tile = 33792B <= 65536B) ---- */
  float* eps = (float*)smem;
  float* Eb = E + (size_t)bz*N_*M_;
  int lg = lane >> 4;                    /* 0..3 */
  int row0 = t >> 5;                     /* 0..7 */
  int c4 = (t & 31)*4;                   /* 0..124 */
  const float* yb = yy + b*M_ + bm*128;
  float4 vy = *(const float4*)(yb + c4);
  float ca0 = 0.f, ca1 = 0.f, ca2 = 0.f, ca3 = 0.f;   /* column partials */
#pragma unroll
  for (int pass = 0; pass < 2; ++pass) {
    __syncthreads();
    if ((w >> 1) == pass) {
#pragma unroll
      for (int fi = 0; fi < 4; ++fi) {
        int nl = lg*4 + fi*16;
#pragma unroll
        for (int fj = 0; fj < 4; ++fj) {
          int ml = wc + (lane & 15) + fj*16;
#pragma unroll
          for (int r = 0; r < 4; ++r)
            eps[(nl + r)*132 + ml] = acc[fi][fj][r];
        }
      }
    }
    __syncthreads();
#pragma unroll
    for (int it = 0; it < 8; ++it) {
      int row = it*8 + row0;
      int gn = bn*128 + pass*64 + row;
      float xv = xx[b*N_ + gn];
      float4 s = *(float4*)&eps[row*132 + c4];
      float4 o;
      o.x = expf(2.f*s.x - xv - vy.x);
      o.y = expf(2.f*s.y - xv - vy.y);
      o.z = expf(2.f*s.z - xv - vy.z);
      o.w = expf(2.f*s.w - xv - vy.w);
      *(float4*)(Eb + (size_t)gn*M_ + bm*128 + c4) = o;
      float rs = o.x + o.y + o.z + o.w;
      float rm2 = fmaxf(fmaxf(o.x, o.y), fmaxf(o.z, o.w));
      ca0 += o.x; ca1 += o.y; ca2 += o.z; ca3 += o.w;
#pragma unroll
      for (int off = 16; off > 0; off >>= 1) {
        rs += __shfl_xor(rs, off, 32);
        rm2 = fmaxf(rm2, __shfl_xor(rm2, off, 32));
      }
      if ((t & 31) == 0) {
        rowps[(size_t)bm*B_*N_ + (size_t)b*N_ + gn] = rs;
        rowpm[(size_t)bm*B_*N_ + (size_t)b*N_ + gn] = rm2;
      }
    }
  }
  __syncthreads();
  float* colsh = (float*)smem;           /* [8][128] */
  colsh[row0*128 + c4+0] = ca0;
  colsh[row0*128 + c4+1] = ca1;
  colsh[row0*128 + c4+2] = ca2;
  colsh[row0*128 + c4+3] = ca3;
  __syncthreads();
  if (t < 128) {
    float s = 0.f;
#pragma unroll
    for (int g = 0; g < 8; ++g) s += colsh[g*128 + t];
    colps[(size_t)bn*B_*M_ + (size_t)b*M_ + bm*128 + t] = s;
  }
}

/* ---- fused: y==0 -> rowZ/rowSmax from row partials; y==1 -> colZ0 ---- */
__global__ __launch_bounds__(256) void kstatcomb(
    const float* __restrict__ rowps, const float* __restrict__ rowpm,
    const float* __restrict__ colps,
    float* __restrict__ rowZf, float* __restrict__ rowSmax,
    float* __restrict__ colZ0f, int b_off)
{
  int i = blockIdx.x*256 + threadIdx.x;
  size_t gi = (size_t)b_off*N_ + i;
  if (blockIdx.y == 0) {
    double s = 0.0; float mx = 0.f;
#pragma unroll
    for (int k = 0; k < 16; ++k) {
      s += (double)rowps[(size_t)k*B_*N_ + gi];
      mx = fmaxf(mx, rowpm[(size_t)k*B_*N_ + gi]);
    }
    float zf = (float)s;
    rowZf[gi] = zf;
    rowSmax[gi] = mx * (1.f / zf);  /* same RN(1/zf) recomputed in kwcorr */
  } else {
    double s = 0.0;
#pragma unroll
    for (int k = 0; k < 16; ++k) s += (double)colps[(size_t)k*B_*M_ + gi];
    colZ0f[gi] = (float)s;
  }
}

/* ---- fused cross pass: one E read -> colSp (sum_n E/rowZ) AND rowSp
        (sum_m E/colZ0), f64 partials; reciprocals precomputed in LDS. ---- */
__global__ __launch_bounds__(256) void kcross(const float* __restrict__ E,
                                              const float* __restrict__ rowZf,
                                              const float* __restrict__ colZ0f,
                                              double* __restrict__ colSp,
                                              double* __restrict__ rowSp, int b_off)
{
  __shared__ float tile[64*129];   /* 33024 B */
  __shared__ double rzinv[64];
  __shared__ double czinv[128];
  __shared__ double shd[256];
  int rc = blockIdx.x, cc = blockIdx.y, bz = blockIdx.z;
  int b = b_off + bz;
  int r0 = rc*64, c0 = cc*128;
  int t = threadIdx.x;
  const float* Eb = E + (size_t)bz*N_*M_;
  {
    int rr = t >> 5, cq = (t & 31)*4;
#pragma unroll
    for (int it = 0; it < 8; ++it) {
      int row = it*8 + rr;
      float4 v = *(const float4*)(Eb + (size_t)(r0+row)*M_ + c0 + cq);
      tile[row*129 + cq+0] = v.x;
      tile[row*129 + cq+1] = v.y;
      tile[row*129 + cq+2] = v.z;
      tile[row*129 + cq+3] = v.w;
    }
  }
  if (t < 64) rzinv[t] = 1.0 / (double)rowZf[(size_t)b*N_ + r0 + t];
  if (t >= 128) czinv[t-128] = 1.0 / (double)colZ0f[(size_t)b*M_ + c0 + (t-128)];
  __syncthreads();
  {
    int j = t & 127, rg = t >> 7;
    double a = 0.0;
    for (int rr = rg*32; rr < rg*32 + 32; ++rr)
      a += (double)tile[rr*129 + j] * rzinv[rr];
    shd[rg*128 + j] = a;
  }
  __syncthreads();
  if (t < 128)
    colSp[(size_t)rc*B_*M_ + (size_t)b*M_ + c0 + t] = shd[t] + shd[128 + t];
  __syncthreads();
  {
    int r = t & 63, h = t >> 6;
    double a = 0.0;
    for (int j = h*32; j < h*32 + 32; ++j)
      a += (double)tile[r*129 + j] * czinv[j];
    shd[h*64 + r] = a;
  }
  __syncthreads();
  if (t < 64)
    rowSp[(size_t)cc*B_*N_ + (size_t)b*N_ + r0 + t] = shd[t] + shd[64+t] + shd[128+t] + shd[192+t];
}

/* ---- fused: y==0 -> col_sum (32 partials); y==1 -> row_sum (16 partials) ---- */
__global__ __launch_bounds__(256) void kcombab(const double* __restrict__ colSp,
                                               const double* __restrict__ rowSp,
                                               double* __restrict__ col_sum,
                                               double* __restrict__ row_sum, int b_off)
{
  int i = blockIdx.x*256 + threadIdx.x;
  if (blockIdx.y == 0) {
    size_t gi = (size_t)b_off*M_ + i;
    double s = 0.0;
    for (int k = 0; k < 32; ++k) s += colSp[(size_t)k*B_*M_ + gi];
    col_sum[gi] = s;
  } else {
    size_t gi = (size_t)b_off*N_ + i;
    double s = 0.0;
    for (int k = 0; k < 16; ++k) s += rowSp[(size_t)k*B_*N_ + gi];
    row_sum[gi] = s;
  }
}

/* ---- exact K-th smallest via rank count; z selects col/row side ---- */
__global__ __launch_bounds__(256) void kkth(const double* __restrict__ col_sum,
                                            const double* __restrict__ row_sum,
                                            double* __restrict__ kth_c,
                                            double* __restrict__ kth_r, int b_off)
{
  __shared__ double sv[2048];
  int b = b_off + blockIdx.y;
  const double* v = (blockIdx.z == 0 ? col_sum : row_sum) + b*2048;
  double* kth = (blockIdx.z == 0 ? kth_c : kth_r);
  int t = threadIdx.x;
  for (int i = t; i < 2048; i += 256) sv[i] = v[i];
  __syncthreads();
  int i = blockIdx.x*256 + t;
  double vi = sv[i];
  int lt = 0, le = 0;
  for (int j = 0; j < 2048; ++j) { double vj = sv[j]; lt += (vj < vi); le += (vj <= vi); }
  if (lt < KSEL && KSEL <= le) kth[b] = vi;
}

/* ---- masks; y selects col/row side ---- */
__global__ __launch_bounds__(256) void kmask(const double* __restrict__ col_sum,
                                             const double* __restrict__ row_sum,
                                             const double* __restrict__ kth_c,
                                             const double* __restrict__ kth_r,
                                             unsigned char* __restrict__ colmask,
                                             unsigned char* __restrict__ rowmask,
                                             float* __restrict__ out, int b_off)
{
  int side = blockIdx.y;
  const double* vals = side ? row_sum : col_sum;
  const double* kth = side ? kth_r : kth_c;
  unsigned char* m8 = side ? rowmask : colmask;
  float* mout = out + (side ? O_MSRC : O_MTGT);
  int i = blockIdx.x*256 + threadIdx.x;
  int b = b_off + i/2048, j = i & 2047;
  bool m = vals[b*2048 + j] < kth[b];
  m8[b*2048 + j] = m ? 1 : 0;
  mout[b*2048 + j] = m ? 1.f : 0.f;
}

/* ---- sparse renorm + vsi + src_corr: float4 register-cached row,
        wave-shuffle reductions, reciprocal multiplies ---- */
__global__ __launch_bounds__(256) void kwcorr(
    const float* __restrict__ E, const float* __restrict__ rowZf,
    const float* __restrict__ rowSmax,
    const unsigned char* __restrict__ rowmask, const unsigned char* __restrict__ colmask,
    const float* __restrict__ tgt, float* __restrict__ vsi,
    float* __restrict__ corrf, float* __restrict__ corr_out, int b_off)
{
  __shared__ float shred[20];
  int r = blockIdx.x, t = threadIdx.x;
  int bz = r / N_, n = r % N_;
  int b = b_off + bz;
  const float* row = E + (size_t)bz*N_*M_ + (size_t)n*M_;
  float rinv = 1.f / rowZf[b*N_+n];       /* bit-identical to kstatcomb's rinv */
  int lane = t & 63, w = t >> 6;
  float rmax = rowSmax[b*N_+n];
  int rm = rowmask[b*N_+n];
  const unsigned char* cm = colmask + b*M_;
  float v0_, v1_, v2_, v3_, v4_, v5_, v6_, v7_;
  unsigned kp = 0;
  float s = 0.f;
  {
    int m0 = t*4;
    float4 e0 = *(const float4*)(row + m0);
    float4 e1 = *(const float4*)(row + m0 + 1024);
    v0_ = e0.x*rinv; v1_ = e0.y*rinv; v2_ = e0.z*rinv; v3_ = e0.w*rinv;
    v4_ = e1.x*rinv; v5_ = e1.y*rinv; v6_ = e1.z*rinv; v7_ = e1.w*rinv;
    uchar4 c0v = *(const uchar4*)(cm + m0);
    uchar4 c1v = *(const uchar4*)(cm + m0 + 1024);
    bool k0 = rm || c0v.x || (v0_ >= rmax); if (k0) { s += v0_; kp |= 1u; }
    bool k1 = rm || c0v.y || (v1_ >= rmax); if (k1) { s += v1_; kp |= 2u; }
    bool k2 = rm || c0v.z || (v2_ >= rmax); if (k2) { s += v2_; kp |= 4u; }
    bool k3 = rm || c0v.w || (v3_ >= rmax); if (k3) { s += v3_; kp |= 8u; }
    bool k4 = rm || c1v.x || (v4_ >= rmax); if (k4) { s += v4_; kp |= 16u; }
    bool k5 = rm || c1v.y || (v5_ >= rmax); if (k5) { s += v5_; kp |= 32u; }
    bool k6 = rm || c1v.z || (v6_ >= rmax); if (k6) { s += v6_; kp |= 64u; }
    bool k7 = rm || c1v.w || (v7_ >= rmax); if (k7) { s += v7_; kp |= 128u; }
  }
#pragma unroll
  for (int off = 32; off; off >>= 1) s += __shfl_xor(s, off, 64);
  if (!lane) shred[w] = s;
  __syncthreads();
  s = shred[0] + shred[1] + shred[2] + shred[3];
  float d = (s < EPS_) ? EPS_ : s;
  float dinv = 1.f / d;
  const float* t0 = tgt + (size_t)b*3*M_;
  float vs = 0.f, a0 = 0.f, a1 = 0.f, a2 = 0.f;
  {
    int m0 = t*4;
    float4 tx0 = *(const float4*)(t0 + m0);
    float4 ty0 = *(const float4*)(t0 + M_ + m0);
    float4 tz0 = *(const float4*)(t0 + 2*M_ + m0);
    float w0 = (kp & 1u)   ? v0_*dinv : 0.f;
    float w1 = (kp & 2u)   ? v1_*dinv : 0.f;
    float w2 = (kp & 4u)   ? v2_*dinv : 0.f;
    float w3 = (kp & 8u)   ? v3_*dinv : 0.f;
    vs += w0+w1+w2+w3;
    a0 += w0*tx0.x + w1*tx0.y + w2*tx0.z + w3*tx0.w;
    a1 += w0*ty0.x + w1*ty0.y + w2*ty0.z + w3*ty0.w;
    a2 += w0*tz0.x + w1*tz0.y + w2*tz0.z + w3*tz0.w;
    float4 tx1 = *(const float4*)(t0 + m0 + 1024);
    float4 ty1 = *(const float4*)(t0 + M_ + m0 + 1024);
    float4 tz1 = *(const float4*)(t0 + 2*M_ + m0 + 1024);
    float w4 = (kp & 16u)  ? v4_*dinv : 0.f;
    float w5 = (kp & 32u)  ? v5_*dinv : 0.f;
    float w6 = (kp & 64u)  ? v6_*dinv : 0.f;
    float w7 = (kp & 128u) ? v7_*dinv : 0.f;
    vs += w4+w5+w6+w7;
    a0 += w4*tx1.x + w5*tx1.y + w6*tx1.z + w7*tx1.w;
    a1 += w4*ty1.x + w5*ty1.y + w6*ty1.z + w7*ty1.w;
    a2 += w4*tz1.x + w5*tz1.y + w6*tz1.z + w7*tz1.w;
  }
#pragma unroll
  for (int off = 32; off; off >>= 1) {
    vs += __shfl_xor(vs, off, 64);
    a0 += __shfl_xor(a0, off, 64);
    a1 += __shfl_xor(a1, off, 64);
    a2 += __shfl_xor(a2, off, 64);
  }
  if (!lane) {
    shred[4 + w] = vs; shred[8 + w] = a0; shred[12 + w] = a1; shred[16 + w] = a2;
  }
  __syncthreads();
  if (!t) {
    float vsT = shred[4]+shred[5]+shred[6]+shred[7];
    float a0T = shred[8]+shred[9]+shred[10]+shred[11];
    float a1T = shred[12]+shred[13]+shred[14]+shred[15];
    float a2T = shred[16]+shred[17]+shred[18]+shred[19];
    vsi[b*N_+n] = rm ? 0.f : vsT;
    size_t o = (size_t)b*3*N_ + n;
    corrf[o] = a0T; corrf[o+N_] = a1T; corrf[o+2*N_] = a2T;
    corr_out[o]      = a0T;
    corr_out[o+N_]   = a1T;
    corr_out[o+2*N_] = a2T;
  }
}

__global__ __launch_bounds__(256) void ksumvsi(const float* __restrict__ vsi,
                                               float* __restrict__ out)
{
  __shared__ double shd[256];
  int b = blockIdx.x;
  double s = 0.0;
  for (int n = threadIdx.x; n < N_; n += 256) s += (double)vsi[b*N_+n];
  s = blk_sumd(s, shd);
  if (!threadIdx.x) out[b] = (float)s;
}

__global__ __launch_bounds__(256) void kweights(const float* __restrict__ vsi,
                                                const float* __restrict__ sumvsi,
                                                float* __restrict__ srcw,
                                                float* __restrict__ wout)
{
  int i = blockIdx.x*256 + threadIdx.x;
  if (i >= B_*N_) return;
  int b = i / N_;
  float w = vsi[i] / sumvsi[b];
  srcw[i] = w;
  wout[i] = w;
}

__global__ __launch_bounds__(256) void kcov(const float* __restrict__ srcw,
                                            const float* __restrict__ src,
                                            const float* __restrict__ corrf,
                                            double* covd, double* cad, double* cbd)
{
  __shared__ double sh[256];
  int b = blockIdx.x, t = threadIdx.x;
  const float* w = srcw + b*N_;
  const float* a = src  + (size_t)b*3*N_;
  const float* bb = corrf + (size_t)b*3*N_;
  double sw = 0.0;
  for (int n = t; n < N_; n += 256) sw += (double)w[n];
  sw = blk_sumd(sw, sh);
  double inv = 1.0/(sw + 1e-5);
  double p0=0,p1=0,p2=0,p3=0,p4=0,p5=0;
  for (int n = t; n < N_; n += 256) {
    double wn = (double)w[n]*inv;
    p0 += (double)a[n]*wn;      p1 += (double)a[N_+n]*wn;   p2 += (double)a[2*N_+n]*wn;
    p3 += (double)bb[n]*wn;     p4 += (double)bb[N_+n]*wn;  p5 += (double)bb[2*N_+n]*wn;
  }
  double ca0 = blk_sumd(p0, sh), ca1 = blk_sumd(p1, sh), ca2 = blk_sumd(p2, sh);
  double cb0 = blk_sumd(p3, sh), cb1 = blk_sumd(p4, sh), cb2 = blk_sumd(p5, sh);
  double c[9] = {0,0,0,0,0,0,0,0,0};
  for (int n = t; n < N_; n += 256) {
    double wn = (double)w[n]*inv;
    double a0 = (double)a[n]-ca0, a1d = (double)a[N_+n]-ca1, a2d = (double)a[2*N_+n]-ca2;
    double b0 = ((double)bb[n]-cb0)*wn, b1 = ((double)bb[N_+n]-cb1)*wn, b2 = ((double)bb[2*N_+n]-cb2)*wn;
    c[0]+=a0*b0; c[1]+=a0*b1; c[2]+=a0*b2;
    c[3]+=a1d*b0; c[4]+=a1d*b1; c[5]+=a1d*b2;
    c[6]+=a2d*b0; c[7]+=a2d*b1; c[8]+=a2d*b2;
  }
  for (int k = 0; k < 9; ++k) {
    double rr = blk_sumd(c[k], sh);
    if (!t) covd[b*9+k] = rr;
  }
  if (!t) {
    cad[b*3+0]=ca0; cad[b*3+1]=ca1; cad[b*3+2]=ca2;
    cbd[b*3+0]=cb0; cbd[b*3+1]=cb1; cbd[b*3+2]=cb2;
  }
}

/* ---- 3x3 Kabsch via Jacobi eigendecomposition of H^T H (f64) ---- */
__global__ void ksvd(const double* __restrict__ covd, const double* __restrict__ cad,
                     const double* __restrict__ cbd, float* out)
{
  int b = threadIdx.x;
  if (b >= B_) return;
  double H[3][3];
  for (int i = 0; i < 3; ++i) for (int j = 0; j < 3; ++j) H[i][j] = covd[b*9+i*3+j];
  double A[3][3];
  for (int i = 0; i < 3; ++i)
    for (int j = 0; j < 3; ++j) {
      double s = 0.0;
      for (int l = 0; l < 3; ++l) s += H[l][i]*H[l][j];
      A[i][j] = s;
    }
  double V[3][3] = {{1,0,0},{0,1,0},{0,0,1}};
  const int PP[3] = {0,0,1}, QQ[3] = {1,2,2};
  for (int sweep = 0; sweep < 24; ++sweep) {
    double off = fabs(A[0][1])+fabs(A[0][2])+fabs(A[1][2]);
    if (off < 1e-28) break;
    for (int r = 0; r < 3; ++r) {
      int p = PP[r], q = QQ[r];
      double apq = A[p][q];
      if (fabs(apq) < 1e-300) continue;
      double th = (A[q][q]-A[p][p])/(2.0*apq);
      double tt = (th >= 0.0 ? 1.0 : -1.0)/(fabs(th)+sqrt(th*th+1.0));
      double cc = 1.0/sqrt(tt*tt+1.0), ss = tt*cc;
      for (int k = 0; k < 3; ++k) {
        double akp = A[k][p], akq = A[k][q];
        A[k][p] = cc*akp - ss*akq; A[k][q] = ss*akp + cc*akq;
      }
      for (int k = 0; k < 3; ++k) {
        double apk = A[p][k], aqk = A[q][k];
        A[p][k] = cc*apk - ss*aqk; A[q][k] = ss*apk + cc*aqk;
      }
      for (int k = 0; k < 3; ++k) {
        double vkp = V[k][p], vkq = V[k][q];
        V[k][p] = cc*vkp - ss*vkq; V[k][q] = ss*vkp + cc*vkq;
      }
    }
  }
  double lam[3] = {A[0][0], A[1][1], A[2][2]};
  int idx[3] = {0,1,2};
  for (int i = 0; i < 2; ++i)
    for (int j = i+1; j < 3; ++j)
      if (lam[idx[j]] > lam[idx[i]]) { int tmp = idx[i]; idx[i] = idx[j]; idx[j] = tmp; }
  double Vs[3][3], sig[3];
  for (int i = 0; i < 3; ++i) {
    for (int k = 0; k < 3; ++k) Vs[k][i] = V[k][idx[i]];
    double l = lam[idx[i]];
    sig[i] = sqrt(l > 0.0 ? l : 0.0);
  }
  double U[3][3];
  for (int i = 0; i < 3; ++i) {
    double inv = sig[i] > 1e-300 ? 1.0/sig[i] : 0.0;
    for (int k = 0; k < 3; ++k) {
      double u = H[k][0]*Vs[0][i] + H[k][1]*Vs[1][i] + H[k][2]*Vs[2][i];
      U[k][i] = u*inv;
    }
  }
  if (sig[2] <= 1e-9*sig[0]) {
    U[0][2] = U[1][0]*U[2][1] - U[2][0]*U[1][1];
    U[1][2] = U[2][0]*U[0][1] - U[0][0]*U[2][1];
    U[2][2] = U[0][0]*U[1][1] - U[1][0]*U[0][1];
  }
  double detH = H[0][0]*(H[1][1]*H[2][2]-H[1][2]*H[2][1])
              - H[0][1]*(H[1][0]*H[2][2]-H[1][2]*H[2][0])
              + H[0][2]*(H[1][0]*H[2][1]-H[1][1]*H[2][0]);
  double s3[3] = {1.0, 1.0, detH > 0.0 ? 1.0 : -1.0};
  double R[3][3];
  for (int d = 0; d < 3; ++d)
    for (int e = 0; e < 3; ++e) {
      double s = 0.0;
      for (int i = 0; i < 3; ++i) s += s3[i]*Vs[d][i]*U[e][i];
      R[d][e] = s;
    }
  double tr[3];
  for (int d = 0; d < 3; ++d)
    tr[d] = cbd[b*3+d] - (R[d][0]*cad[b*3+0] + R[d][1]*cad[b*3+1] + R[d][2]*cad[b*3+2]);
  for (int d = 0; d < 3; ++d)
    for (int e = 0; e < 3; ++e)
      out[O_ROT + b*9 + d*3 + e] = (float)R[d][e];
  for (int d = 0; d < 3; ++d)
    out[O_TR + b*3 + d] = (float)tr[d];
}

__global__ void kfail(float* out, float v) { out[0] = v; }

extern "C" void kernel_launch(void* const* d_in, const int* in_sizes, int n_in,
                              void* d_out, int out_size, void* d_ws, size_t ws_size,
                              hipStream_t stream) {
  float* out = (float*)d_out;
  (void)out_size;

  /* input-order auto-detect: dict (src,tgt,src_emb,tgt_emb) vs alphabetical */
  int i_tgt = 1, i_semb = 2;
  if (n_in == 4 && in_sizes[1] == B_*C_*N_) { i_semb = 1; i_tgt = 2; }
  const float* src  = (const float*)d_in[0];
  const float* tgt  = (const float*)d_in[i_tgt];
  const float* semb = (const float*)d_in[i_semb];
  const float* temb = (const float*)d_in[3];

  char* w = (char*)d_ws;
  auto alloc = [&](size_t bytes) { char* p = w; w += (bytes + 255)/256*256; return p; };
  float*  sqpartA = (float*)alloc((size_t)CS_*B_*N_*4);
  float*  sqpartB = (float*)alloc((size_t)CS_*B_*N_*4);
  float*  xx      = (float*)alloc((size_t)B_*N_*4);
  float*  yy      = (float*)alloc((size_t)B_*M_*4);
  float*  rowZf   = (float*)alloc((size_t)B_*N_*4);
  float*  rowSmax = (float*)alloc((size_t)B_*N_*4);
  float*  colZ0f  = (float*)alloc((size_t)B_*M_*4);
  float*  rowps   = (float*)alloc((size_t)16*B_*N_*4);   /* partial-major [bm][b][n] */
  float*  rowpm   = (float*)alloc((size_t)16*B_*N_*4);
  float*  colps   = (float*)alloc((size_t)16*B_*M_*4);   /* [bn][b][m] */
  double* colSp   = (double*)alloc((size_t)32*B_*M_*8);  /* [rc][b][m] */
  double* rowSp   = (double*)alloc((size_t)16*B_*N_*8);  /* [cc][b][n] */
  double* col_sum = (double*)alloc((size_t)B_*M_*8);
  double* row_sum = (double*)alloc((size_t)B_*N_*8);
  double* kth_c   = (double*)alloc((size_t)B_*8);
  double* kth_r   = (double*)alloc((size_t)B_*8);
  unsigned char* rowmask = (unsigned char*)alloc((size_t)B_*N_);
  unsigned char* colmask = (unsigned char*)alloc((size_t)B_*M_);
  float*  vsi     = (float*)alloc((size_t)B_*N_*4);
  float*  srcw    = (float*)alloc((size_t)B_*N_*4);
  float*  sumvsi  = (float*)alloc((size_t)B_*4);
  float*  corrf   = (float*)alloc((size_t)B_*3*N_*4);
  double* covd = (double*)alloc((size_t)B_*9*8);
  double* cad  = (double*)alloc((size_t)B_*3*8);
  double* cbd  = (double*)alloc((size_t)B_*3*8);
  /* split-bf16 operand arrays [B][pos][C] */
  unsigned short* Ahg = (unsigned short*)alloc((size_t)B_*N_*C_*2);
  unsigned short* Alg = (unsigned short*)alloc((size_t)B_*N_*C_*2);
  unsigned short* Bhg = (unsigned short*)alloc((size_t)B_*M_*C_*2);
  unsigned short* Blg = (unsigned short*)alloc((size_t)B_*M_*C_*2);

  size_t used = (size_t)(w - (char*)d_ws);
  size_t rem = ws_size > used ? ws_size - used : 0;
  size_t oneE = (size_t)N_*M_*sizeof(float);
  int bc = (int)(rem / oneE);
  if (bc < 1) { kfail<<<1, 1, 0, stream>>>(out, 32768.f); return; }
  if (bc > B_) bc = B_;
  float* E = (float*)w;

  /* split + transpose both embeddings (fused sum-of-squares partials) */
  ksplit<<<dim3(N_/64, C_/64, 2*B_), 256, 0, stream>>>(semb, temb, Ahg, Alg, Bhg, Blg,
                                                       sqpartA, sqpartB);
  ksqcomb<<<dim3((B_*N_)/256, 2), 256, 0, stream>>>(sqpartA, sqpartB, xx, yy);

  for (int b0 = 0; b0 < B_; b0 += bc) {
    int cur = (B_ - b0 < bc) ? (B_ - b0) : bc;
    kgemm_mfma<<<dim3(N_/128, M_/128, cur), 256, 0, stream>>>(Ahg, Alg, Bhg, Blg,
                                                              xx, yy, E, rowps, rowpm, colps, b0);
    kstatcomb<<<dim3(cur*N_/256, 2), 256, 0, stream>>>(rowps, rowpm, colps,
                                                       rowZf, rowSmax, colZ0f, b0);
    kcross   <<<dim3(N_/64, M_/128, cur), 256, 0, stream>>>(E, rowZf, colZ0f, colSp, rowSp, b0);
    kcombab  <<<dim3(cur*M_/256, 2), 256, 0, stream>>>(colSp, rowSp, col_sum, row_sum, b0);
    kkth     <<<dim3(8, cur, 2), 256, 0, stream>>>(col_sum, row_sum, kth_c, kth_r, b0);
    kmask    <<<dim3(cur*8, 2), 256, 0, stream>>>(col_sum, row_sum, kth_c, kth_r,
                                                  colmask, rowmask, out, b0);
    kwcorr   <<<cur*N_, 256, 0, stream>>>(E, rowZf, rowSmax, rowmask, colmask, tgt,
                                          vsi, corrf, out + O_CORR, b0);
  }

  ksumvsi <<<B_, 256, 0, stream>>>(vsi, sumvsi);
  kweights<<<(B_*N_+255)/256, 256, 0, stream>>>(vsi, sumvsi, srcw, out + O_W);
  kcov    <<<B_, 256, 0, stream>>>(srcw, src, corrf, covd, cad, cbd);
  ksvd    <<<1, 64, 0, stream>>>(covd, cad, cbd, out);
}